// Round 1
// baseline (1531.646 us; speedup 1.0000x reference)
//
#include <hip/hip_runtime.h>

#define NN 50000
#define EE 800000
#define LMD 768
#define HD 192
#define SLOPE 0.01f

__device__ __forceinline__ float lrelu(float v){ return v > 0.f ? v : SLOPE * v; }

// ---------- big branches: four [N,768] -> [N,32] GEMMs, lrelu, write into h ----------
__global__ __launch_bounds__(256) void k_big_branch(
    const float* __restrict__ des, const float* __restrict__ twt,
    const float* __restrict__ prex, const float* __restrict__ xx,
    const float* __restrict__ Wdes, const float* __restrict__ bdes,
    const float* __restrict__ Wtext, const float* __restrict__ btext,
    const float* __restrict__ Wtweet, const float* __restrict__ btweet,
    const float* __restrict__ Wtr, const float* __restrict__ btr,
    float* __restrict__ h)
{
    int row = blockIdx.x * 256 + threadIdx.x;
    if (row >= NN) return;
    const float* in; const float* W; const float* b; int cb;
    switch (blockIdx.y) {
      case 0:  in = des;  W = Wdes;   b = bdes;   cb = 64;  break;
      case 1:  in = twt;  W = Wtext;  b = btext;  cb = 96;  break;
      case 2:  in = prex; W = Wtweet; b = btweet; cb = 128; break;
      default: in = xx;   W = Wtr;    b = btr;    cb = 160; break;
    }
    float acc[32];
    #pragma unroll
    for (int c = 0; c < 32; ++c) acc[c] = 0.f;
    const float4* a4 = reinterpret_cast<const float4*>(in + (size_t)row * LMD);
    for (int k = 0; k < LMD / 4; ++k) {
        float4 a = a4[k];
        #pragma unroll
        for (int c = 0; c < 32; ++c) {
            const float4 w = *reinterpret_cast<const float4*>(W + c * LMD + 4 * k);
            acc[c] += a.x * w.x + a.y * w.y + a.z * w.z + a.w * w.w;
        }
    }
    float* hp = h + (size_t)row * HD + cb;
    #pragma unroll
    for (int c = 0; c < 32; ++c) hp[c] = lrelu(acc[c] + b[c]);
}

// ---------- small branches: num_prop [N,5]->[N,32] (cols 0..31), num_category [N,1]->[N,32] (cols 32..63) ----------
__global__ __launch_bounds__(256) void k_small_branch(
    const float* __restrict__ nprop, const float* __restrict__ ncat,
    const float* __restrict__ Wp, const float* __restrict__ bp,
    const float* __restrict__ Wc, const float* __restrict__ bc,
    float* __restrict__ h)
{
    int idx = blockIdx.x * 256 + threadIdx.x;
    if (idx >= NN * 64) return;
    int row = idx >> 6, c = idx & 63;
    float acc;
    if (c < 32) {
        acc = bp[c];
        #pragma unroll
        for (int k = 0; k < 5; ++k) acc += nprop[row * 5 + k] * Wp[c * 5 + k];
    } else {
        int cc = c - 32;
        acc = bc[cc] + ncat[row] * Wc[cc];
    }
    h[(size_t)row * HD + c] = lrelu(acc);
}

// ---------- generic row-per-lane GEMM: out[M, ldo(+cb)] = (lrelu)(in[M,K] @ W[.,K]^T (+bias)) ----------
template<int K, int NC, bool BIAS, bool LRELU>
__global__ __launch_bounds__(256) void k_gemm_rows(
    const float* __restrict__ in, const float* __restrict__ W,
    const float* __restrict__ bias, float* __restrict__ out,
    int M, int ldo)
{
    int row = blockIdx.x * 256 + threadIdx.x;
    if (row >= M) return;
    int cb = blockIdx.y * NC;
    float acc[NC];
    #pragma unroll
    for (int c = 0; c < NC; ++c) acc[c] = 0.f;
    const float4* a4 = reinterpret_cast<const float4*>(in + (size_t)row * K);
    for (int k = 0; k < K / 4; ++k) {
        float4 a = a4[k];
        #pragma unroll
        for (int c = 0; c < NC; ++c) {
            const float4 w = *reinterpret_cast<const float4*>(W + (size_t)(cb + c) * K + 4 * k);
            acc[c] += a.x * w.x + a.y * w.y + a.z * w.z + a.w * w.w;
        }
    }
    float* op = out + (size_t)row * ldo + cb;
    #pragma unroll
    for (int c = 0; c < NC; ++c) {
        float v = acc[c] + (BIAS ? bias[cb + c] : 0.f);
        op[c] = LRELU ? lrelu(v) : v;
    }
}

// ---------- graph structure ----------
__global__ void k_count(const int* __restrict__ ei, int* __restrict__ deg)
{
    int e = blockIdx.x * 256 + threadIdx.x;
    if (e < EE) atomicAdd(&deg[ei[EE + e]], 1);
}

__global__ void k_deginv(const int* __restrict__ deg, float* __restrict__ dinv, float* __restrict__ invdeg)
{
    int v = blockIdx.x * 256 + threadIdx.x;
    if (v < NN) {
        float d = (float)(deg[v] + 1);
        dinv[v] = rsqrtf(d);
        invdeg[v] = 1.0f / d;
    }
}

__global__ __launch_bounds__(1024) void k_scan1(const int* __restrict__ deg, int* __restrict__ rp, int* __restrict__ part)
{
    __shared__ int sh[1024];
    int tid = threadIdx.x, i = blockIdx.x * 1024 + tid;
    int x = (i < NN) ? deg[i] : 0;
    sh[tid] = x;
    __syncthreads();
    for (int off = 1; off < 1024; off <<= 1) {
        int y = (tid >= off) ? sh[tid - off] : 0;
        __syncthreads();
        sh[tid] += y;
        __syncthreads();
    }
    if (i < NN) rp[i] = sh[tid] - x;       // exclusive
    if (tid == 1023) part[blockIdx.x] = sh[tid];
}

__global__ void k_scan2(int* part, int nb, int* rp)
{
    if (threadIdx.x == 0 && blockIdx.x == 0) {
        int run = 0;
        for (int b = 0; b < nb; ++b) { int t = part[b]; part[b] = run; run += t; }
        rp[NN] = run;
    }
}

__global__ void k_scan3(int* rp, const int* __restrict__ part)
{
    int i = blockIdx.x * 256 + threadIdx.x;
    if (i < NN) rp[i] += part[i >> 10];
}

__global__ void k_fill(const int* __restrict__ ei, const float* __restrict__ dinv,
                       int* __restrict__ cursor, int* __restrict__ cs, float* __restrict__ nrm)
{
    int e = blockIdx.x * 256 + threadIdx.x;
    if (e >= EE) return;
    int s = ei[e], d = ei[EE + e];
    int pos = atomicAdd(&cursor[d], 1);
    cs[pos] = s;
    nrm[pos] = dinv[s] * dinv[d];
}

// ---------- GCN aggregation: out[v] = sum_in hW[src]*norm + hW[v]*invdeg[v] + bias ----------
__global__ __launch_bounds__(192) void k_agg(const float* __restrict__ hW,
    const int* __restrict__ rp, const int* __restrict__ cs, const float* __restrict__ nrm,
    const float* __restrict__ invdeg, const float* __restrict__ bias, float* __restrict__ out)
{
    int v = blockIdx.x;
    int f = threadIdx.x;
    int s0 = rp[v], s1 = rp[v + 1];
    float acc = hW[(size_t)v * HD + f] * invdeg[v] + bias[f];
    for (int i = s0; i < s1; ++i)
        acc += hW[(size_t)cs[i] * HD + f] * nrm[i];
    out[(size_t)v * HD + f] = acc;
}

// ---------- final [N,96] -> [N,2] ----------
__global__ __launch_bounds__(256) void k_o2(const float* __restrict__ em,
    const float* __restrict__ W, const float* __restrict__ b, float* __restrict__ out)
{
    int row = blockIdx.x * 256 + threadIdx.x;
    if (row >= NN) return;
    const float4* e4 = reinterpret_cast<const float4*>(em + (size_t)row * 96);
    float a0 = b[0], a1 = b[1];
    for (int k = 0; k < 24; ++k) {
        float4 v = e4[k];
        const float4 w0 = *reinterpret_cast<const float4*>(W + 4 * k);
        const float4 w1 = *reinterpret_cast<const float4*>(W + 96 + 4 * k);
        a0 += v.x * w0.x + v.y * w0.y + v.z * w0.z + v.w * w0.w;
        a1 += v.x * w1.x + v.y * w1.y + v.z * w1.z + v.w * w1.w;
    }
    out[row * 2 + 0] = a0;
    out[row * 2 + 1] = a1;
}

extern "C" void kernel_launch(void* const* d_in, const int* in_sizes, int n_in,
                              void* d_out, int out_size, void* d_ws, size_t ws_size,
                              hipStream_t stream)
{
    const float* pre_x = (const float*)d_in[0];
    const float* x     = (const float*)d_in[1];
    const int*   ei    = (const int*)d_in[2];
    // d_in[3] edge_type: unused by reference
    const float* nprop = (const float*)d_in[4];
    const float* ncat  = (const float*)d_in[5];
    const float* des   = (const float*)d_in[6];
    const float* twt   = (const float*)d_in[7];
    const float* W_des  = (const float*)d_in[8],  *b_des  = (const float*)d_in[9];
    const float* W_tw   = (const float*)d_in[10], *b_tw   = (const float*)d_in[11];
    const float* W_tr   = (const float*)d_in[12], *b_tr   = (const float*)d_in[13];
    const float* W_prop = (const float*)d_in[14], *b_prop = (const float*)d_in[15];
    const float* W_cat  = (const float*)d_in[16], *b_cat  = (const float*)d_in[17];
    const float* W_text = (const float*)d_in[18], *b_text = (const float*)d_in[19];
    const float* W_in   = (const float*)d_in[20], *b_in   = (const float*)d_in[21];
    const float* W_c1   = (const float*)d_in[22], *b_c1   = (const float*)d_in[23];
    const float* W_c2   = (const float*)d_in[24], *b_c2   = (const float*)d_in[25];
    const float* W_o1   = (const float*)d_in[26], *b_o1   = (const float*)d_in[27];
    const float* W_o2   = (const float*)d_in[28], *b_o2   = (const float*)d_in[29];

    char* base = (char*)d_ws;
    size_t off = 0;
    auto alloc = [&](size_t bytes) -> char* {
        char* p = base + off;
        off = (off + bytes + 255) & ~(size_t)255;
        return p;
    };
    float* hA     = (float*)alloc((size_t)NN * HD * 4);
    float* hB     = (float*)alloc((size_t)NN * HD * 4);
    float* hC     = (float*)alloc((size_t)NN * HD * 4);
    float* dinv   = (float*)alloc((size_t)NN * 4);
    float* invdeg = (float*)alloc((size_t)NN * 4);
    int*   deg    = (int*)alloc((size_t)NN * 4);
    int*   rp     = (int*)alloc((size_t)(NN + 1) * 4);
    int*   cursor = (int*)alloc((size_t)NN * 4);
    int*   part   = (int*)alloc(64 * 4);
    int*   cs     = (int*)alloc((size_t)EE * 4);
    float* nrm    = (float*)alloc((size_t)EE * 4);
    (void)ws_size; (void)in_sizes; (void)n_in; (void)out_size;

    float* outp = (float*)d_out;            // [N,2]
    float* em   = outp + (size_t)NN * 2;    // [N,96]

    const int rb = (NN + 255) / 256;        // 196
    const int eb = (EE + 255) / 256;        // 3125
    const int nb1024 = (NN + 1023) / 1024;  // 49

    // ---- graph structure (independent of feature path) ----
    hipMemsetAsync(deg, 0, (size_t)NN * 4, stream);
    hipLaunchKernelGGL(k_count,  dim3(eb), dim3(256), 0, stream, ei, deg);
    hipLaunchKernelGGL(k_deginv, dim3(rb), dim3(256), 0, stream, deg, dinv, invdeg);
    hipLaunchKernelGGL(k_scan1,  dim3(nb1024), dim3(1024), 0, stream, deg, rp, part);
    hipLaunchKernelGGL(k_scan2,  dim3(1), dim3(1), 0, stream, part, nb1024, rp);
    hipLaunchKernelGGL(k_scan3,  dim3(rb), dim3(256), 0, stream, rp, part);
    hipMemcpyAsync(cursor, rp, (size_t)NN * 4, hipMemcpyDeviceToDevice, stream);
    hipLaunchKernelGGL(k_fill,   dim3(eb), dim3(256), 0, stream, ei, dinv, cursor, cs, nrm);

    // ---- feature path ----
    hipLaunchKernelGGL(k_big_branch, dim3(rb, 4), dim3(256), 0, stream,
        des, twt, pre_x, x, W_des, b_des, W_text, b_text, W_tw, b_tw, W_tr, b_tr, hA);
    hipLaunchKernelGGL(k_small_branch, dim3((NN * 64 + 255) / 256), dim3(256), 0, stream,
        nprop, ncat, W_prop, b_prop, W_cat, b_cat, hA);

    // h1 = lrelu(hA @ W_in^T + b_in)
    hipLaunchKernelGGL((k_gemm_rows<192, 48, true, true>),  dim3(rb, 4), dim3(256), 0, stream,
        hA, W_in, b_in, hB, NN, HD);
    // hW1 = hB @ W_c1^T
    hipLaunchKernelGGL((k_gemm_rows<192, 48, false, false>), dim3(rb, 4), dim3(256), 0, stream,
        hB, W_c1, nullptr, hC, NN, HD);
    // conv1 out -> hA
    hipLaunchKernelGGL(k_agg, dim3(NN), dim3(192), 0, stream, hC, rp, cs, nrm, invdeg, b_c1, hA);
    // hW2 = hA @ W_c2^T
    hipLaunchKernelGGL((k_gemm_rows<192, 48, false, false>), dim3(rb, 4), dim3(256), 0, stream,
        hA, W_c2, nullptr, hB, NN, HD);
    // conv2 out -> hC
    hipLaunchKernelGGL(k_agg, dim3(NN), dim3(192), 0, stream, hB, rp, cs, nrm, invdeg, b_c2, hC);

    // em = lrelu(hC @ W_o1^T + b_o1)   [N,96] straight into d_out
    hipLaunchKernelGGL((k_gemm_rows<192, 48, true, true>),  dim3(rb, 2), dim3(256), 0, stream,
        hC, W_o1, b_o1, em, NN, 96);
    // out = em @ W_o2^T + b_o2
    hipLaunchKernelGGL(k_o2, dim3(rb), dim3(256), 0, stream, em, W_o2, b_o2, outp);
}

// Round 2
// 723.393 us; speedup vs baseline: 2.1173x; 2.1173x over previous
//
#include <hip/hip_runtime.h>

#define NN 50000
#define EE 800000
#define LMD 768
#define HD 192
#define SLOPE 0.01f

typedef short bf16x8 __attribute__((ext_vector_type(8)));
typedef float f32x4 __attribute__((ext_vector_type(4)));
typedef unsigned short u16;

__device__ __forceinline__ float lrelu(float v){ return v > 0.f ? v : SLOPE * v; }

// fp32 -> bf16 round-to-nearest-even
__device__ __forceinline__ u16 f2bf(float f){
    unsigned u = __float_as_uint(f);
    u += 0x7FFF + ((u >> 16) & 1u);
    return (u16)(u >> 16);
}

// ---- stage [128 rows x 64 k] fp32 -> bf16 swizzled LDS (As: 128*64 u16) ----
// LDS layout: row r, k kk: u16 index = r*64 + ((kk/8) ^ (r&7))*8 + (kk%8)
__device__ __forceinline__ void stage_A(u16* As, const float* __restrict__ A,
                                        int rowBase, int k0, int K, int t)
{
    #pragma unroll
    for (int i = 0; i < 8; ++i) {
        int idx = i * 256 + t;
        int r = idx >> 4, f4c = idx & 15;
        int g = rowBase + r; if (g >= NN) g = NN - 1;
        const float4 v = *reinterpret_cast<const float4*>(A + (size_t)g * K + k0 + f4c * 4);
        int base = r * 64 + (((f4c >> 1) ^ (r & 7)) << 3) + ((f4c & 1) << 2);
        *reinterpret_cast<ushort4*>(As + base) =
            make_ushort4(f2bf(v.x), f2bf(v.y), f2bf(v.z), f2bf(v.w));
    }
}

// ---- stage [32 cols x 64 k] of W (torch [out,in] row-major) -> bf16 swizzled LDS ----
__device__ __forceinline__ void stage_B(u16* Bs, const float* __restrict__ W,
                                        int wColBase, int k0, int K, int t)
{
    #pragma unroll
    for (int i = 0; i < 2; ++i) {
        int idx = i * 256 + t;
        int c = idx >> 4, f4c = idx & 15;
        const float4 v = *reinterpret_cast<const float4*>(W + (size_t)(wColBase + c) * K + k0 + f4c * 4);
        int base = c * 64 + (((f4c >> 1) ^ (c & 7)) << 3) + ((f4c & 1) << 2);
        *reinterpret_cast<ushort4*>(Bs + base) =
            make_ushort4(f2bf(v.x), f2bf(v.y), f2bf(v.z), f2bf(v.w));
    }
}

// ---- block: 256 thr = 4 waves, tile 128 rows x 32 cols, K-loop BK=64 ----
template<int KSTEPS, bool BIAS, bool LRELU>
__device__ __forceinline__ void gemm_body(const float* __restrict__ A, const float* __restrict__ W,
                                          const float* __restrict__ bias, float* __restrict__ out,
                                          int K, int ldo, int wColBase, int outColBase, int biasOff)
{
    __shared__ u16 As[128 * 64];
    __shared__ u16 Bs[32 * 64];
    const int t = threadIdx.x;
    const int rowBase = blockIdx.x * 128;
    const int w = t >> 6, l = t & 63;

    f32x4 acc[2][2] = {};

    for (int s = 0; s < KSTEPS; ++s) {
        __syncthreads();                       // previous iter's LDS reads done
        stage_A(As, A, rowBase, s * 64, K, t);
        stage_B(Bs, W, wColBase, s * 64, K, t);
        __syncthreads();

        #pragma unroll
        for (int kb = 0; kb < 2; ++kb) {
            bf16x8 af[2], bfr[2];
            #pragma unroll
            for (int rb = 0; rb < 2; ++rb) {
                int r = w * 32 + rb * 16 + (l & 15);
                int chunk = (kb * 4 + (l >> 4)) ^ (r & 7);
                af[rb] = *reinterpret_cast<bf16x8*>(As + r * 64 + chunk * 8);
            }
            #pragma unroll
            for (int cb = 0; cb < 2; ++cb) {
                int c = cb * 16 + (l & 15);
                int chunk = (kb * 4 + (l >> 4)) ^ (c & 7);
                bfr[cb] = *reinterpret_cast<bf16x8*>(Bs + c * 64 + chunk * 8);
            }
            #pragma unroll
            for (int rb = 0; rb < 2; ++rb)
                #pragma unroll
                for (int cb = 0; cb < 2; ++cb)
                    acc[rb][cb] = __builtin_amdgcn_mfma_f32_16x16x32_bf16(af[rb], bfr[cb], acc[rb][cb], 0, 0, 0);
        }
    }

    // C/D layout (m89): col = lane&15, row = (lane>>4)*4 + reg
    #pragma unroll
    for (int rb = 0; rb < 2; ++rb) {
        int r0 = rowBase + w * 32 + rb * 16 + (l >> 4) * 4;
        #pragma unroll
        for (int cb = 0; cb < 2; ++cb) {
            int cl = cb * 16 + (l & 15);
            float bv = BIAS ? bias[biasOff + cl] : 0.f;
            #pragma unroll
            for (int rg = 0; rg < 4; ++rg) {
                int row = r0 + rg;
                if (row < NN) {
                    float v = acc[rb][cb][rg] + bv;
                    out[(size_t)row * ldo + outColBase + cl] = LRELU ? lrelu(v) : v;
                }
            }
        }
    }
}

// ---- four big branches: [N,768] -> [N,32] each, into h cols 64..191 ----
__global__ __launch_bounds__(256) void k_branch_mfma(
    const float* __restrict__ des, const float* __restrict__ twt,
    const float* __restrict__ prex, const float* __restrict__ xx,
    const float* __restrict__ Wdes, const float* __restrict__ bdes,
    const float* __restrict__ Wtext, const float* __restrict__ btext,
    const float* __restrict__ Wtweet, const float* __restrict__ btweet,
    const float* __restrict__ Wtr, const float* __restrict__ btr,
    float* __restrict__ h)
{
    const float* A; const float* W; const float* b; int cb;
    switch (blockIdx.y) {
      case 0:  A = des;  W = Wdes;   b = bdes;   cb = 64;  break;
      case 1:  A = twt;  W = Wtext;  b = btext;  cb = 96;  break;
      case 2:  A = prex; W = Wtweet; b = btweet; cb = 128; break;
      default: A = xx;   W = Wtr;    b = btr;    cb = 160; break;
    }
    gemm_body<12, true, true>(A, W, b, h, LMD, HD, 0, cb, 0);
}

// ---- H-GEMMs: [N,192] @ W[NC,192]^T, NC = gridDim.y*32 ----
template<bool BIAS, bool LRELU>
__global__ __launch_bounds__(256) void k_hgemm(
    const float* __restrict__ A, const float* __restrict__ W,
    const float* __restrict__ bias, float* __restrict__ out, int ldo)
{
    int cb = blockIdx.y * 32;
    gemm_body<3, BIAS, LRELU>(A, W, bias, out, HD, ldo, cb, cb, cb);
}

// ---------- small branches: num_prop [N,5]->cols 0..31, num_category [N,1]->cols 32..63 ----------
__global__ __launch_bounds__(256) void k_small_branch(
    const float* __restrict__ nprop, const float* __restrict__ ncat,
    const float* __restrict__ Wp, const float* __restrict__ bp,
    const float* __restrict__ Wc, const float* __restrict__ bc,
    float* __restrict__ h)
{
    int idx = blockIdx.x * 256 + threadIdx.x;
    if (idx >= NN * 64) return;
    int row = idx >> 6, c = idx & 63;
    float acc;
    if (c < 32) {
        acc = bp[c];
        #pragma unroll
        for (int k = 0; k < 5; ++k) acc += nprop[row * 5 + k] * Wp[c * 5 + k];
    } else {
        int cc = c - 32;
        acc = bc[cc] + ncat[row] * Wc[cc];
    }
    h[(size_t)row * HD + c] = lrelu(acc);
}

// ---------- graph structure ----------
__global__ void k_count(const int* __restrict__ ei, int* __restrict__ deg)
{
    int e = blockIdx.x * 256 + threadIdx.x;
    if (e < EE) atomicAdd(&deg[ei[EE + e]], 1);
}

__global__ void k_deginv(const int* __restrict__ deg, float* __restrict__ dinv, float* __restrict__ invdeg)
{
    int v = blockIdx.x * 256 + threadIdx.x;
    if (v < NN) {
        float d = (float)(deg[v] + 1);
        dinv[v] = rsqrtf(d);
        invdeg[v] = 1.0f / d;
    }
}

__global__ __launch_bounds__(1024) void k_scan1(const int* __restrict__ deg, int* __restrict__ rp, int* __restrict__ part)
{
    __shared__ int sh[1024];
    int tid = threadIdx.x, i = blockIdx.x * 1024 + tid;
    int x = (i < NN) ? deg[i] : 0;
    sh[tid] = x;
    __syncthreads();
    for (int off = 1; off < 1024; off <<= 1) {
        int y = (tid >= off) ? sh[tid - off] : 0;
        __syncthreads();
        sh[tid] += y;
        __syncthreads();
    }
    if (i < NN) rp[i] = sh[tid] - x;       // exclusive
    if (tid == 1023) part[blockIdx.x] = sh[tid];
}

__global__ void k_scan2(int* part, int nb, int* rp)
{
    if (threadIdx.x == 0 && blockIdx.x == 0) {
        int run = 0;
        for (int b = 0; b < nb; ++b) { int t = part[b]; part[b] = run; run += t; }
        rp[NN] = run;
    }
}

__global__ void k_scan3(int* rp, const int* __restrict__ part)
{
    int i = blockIdx.x * 256 + threadIdx.x;
    if (i < NN) rp[i] += part[i >> 10];
}

__global__ void k_fill(const int* __restrict__ ei, const float* __restrict__ dinv,
                       int* __restrict__ cursor, int* __restrict__ cs, float* __restrict__ nrm)
{
    int e = blockIdx.x * 256 + threadIdx.x;
    if (e >= EE) return;
    int s = ei[e], d = ei[EE + e];
    int pos = atomicAdd(&cursor[d], 1);
    cs[pos] = s;
    nrm[pos] = dinv[s] * dinv[d];
}

// ---------- GCN aggregation ----------
__global__ __launch_bounds__(192) void k_agg(const float* __restrict__ hW,
    const int* __restrict__ rp, const int* __restrict__ cs, const float* __restrict__ nrm,
    const float* __restrict__ invdeg, const float* __restrict__ bias, float* __restrict__ out)
{
    int v = blockIdx.x;
    int f = threadIdx.x;
    int s0 = rp[v], s1 = rp[v + 1];
    float acc = hW[(size_t)v * HD + f] * invdeg[v] + bias[f];
    for (int i = s0; i < s1; ++i)
        acc += hW[(size_t)cs[i] * HD + f] * nrm[i];
    out[(size_t)v * HD + f] = acc;
}

// ---------- final [N,96] -> [N,2] ----------
__global__ __launch_bounds__(256) void k_o2(const float* __restrict__ em,
    const float* __restrict__ W, const float* __restrict__ b, float* __restrict__ out)
{
    int row = blockIdx.x * 256 + threadIdx.x;
    if (row >= NN) return;
    const float4* e4 = reinterpret_cast<const float4*>(em + (size_t)row * 96);
    float a0 = b[0], a1 = b[1];
    for (int k = 0; k < 24; ++k) {
        float4 v = e4[k];
        const float4 w0 = *reinterpret_cast<const float4*>(W + 4 * k);
        const float4 w1 = *reinterpret_cast<const float4*>(W + 96 + 4 * k);
        a0 += v.x * w0.x + v.y * w0.y + v.z * w0.z + v.w * w0.w;
        a1 += v.x * w1.x + v.y * w1.y + v.z * w1.z + v.w * w1.w;
    }
    out[row * 2 + 0] = a0;
    out[row * 2 + 1] = a1;
}

extern "C" void kernel_launch(void* const* d_in, const int* in_sizes, int n_in,
                              void* d_out, int out_size, void* d_ws, size_t ws_size,
                              hipStream_t stream)
{
    const float* pre_x = (const float*)d_in[0];
    const float* x     = (const float*)d_in[1];
    const int*   ei    = (const int*)d_in[2];
    const float* nprop = (const float*)d_in[4];
    const float* ncat  = (const float*)d_in[5];
    const float* des   = (const float*)d_in[6];
    const float* twt   = (const float*)d_in[7];
    const float* W_des  = (const float*)d_in[8],  *b_des  = (const float*)d_in[9];
    const float* W_tw   = (const float*)d_in[10], *b_tw   = (const float*)d_in[11];
    const float* W_tr   = (const float*)d_in[12], *b_tr   = (const float*)d_in[13];
    const float* W_prop = (const float*)d_in[14], *b_prop = (const float*)d_in[15];
    const float* W_cat  = (const float*)d_in[16], *b_cat  = (const float*)d_in[17];
    const float* W_text = (const float*)d_in[18], *b_text = (const float*)d_in[19];
    const float* W_in   = (const float*)d_in[20], *b_in   = (const float*)d_in[21];
    const float* W_c1   = (const float*)d_in[22], *b_c1   = (const float*)d_in[23];
    const float* W_c2   = (const float*)d_in[24], *b_c2   = (const float*)d_in[25];
    const float* W_o1   = (const float*)d_in[26], *b_o1   = (const float*)d_in[27];
    const float* W_o2   = (const float*)d_in[28], *b_o2   = (const float*)d_in[29];

    char* base = (char*)d_ws;
    size_t off = 0;
    auto alloc = [&](size_t bytes) -> char* {
        char* p = base + off;
        off = (off + bytes + 255) & ~(size_t)255;
        return p;
    };
    float* hA     = (float*)alloc((size_t)NN * HD * 4);
    float* hB     = (float*)alloc((size_t)NN * HD * 4);
    float* hC     = (float*)alloc((size_t)NN * HD * 4);
    float* dinv   = (float*)alloc((size_t)NN * 4);
    float* invdeg = (float*)alloc((size_t)NN * 4);
    int*   deg    = (int*)alloc((size_t)NN * 4);
    int*   rp     = (int*)alloc((size_t)(NN + 1) * 4);
    int*   cursor = (int*)alloc((size_t)NN * 4);
    int*   part   = (int*)alloc(64 * 4);
    int*   cs     = (int*)alloc((size_t)EE * 4);
    float* nrm    = (float*)alloc((size_t)EE * 4);
    (void)ws_size; (void)in_sizes; (void)n_in; (void)out_size;

    float* outp = (float*)d_out;            // [N,2]
    float* em   = outp + (size_t)NN * 2;    // [N,96]

    const int rb   = (NN + 255) / 256;      // 196
    const int rb128 = (NN + 127) / 128;     // 391
    const int eb   = (EE + 255) / 256;      // 3125
    const int nb1024 = (NN + 1023) / 1024;  // 49

    // ---- graph structure ----
    hipMemsetAsync(deg, 0, (size_t)NN * 4, stream);
    hipLaunchKernelGGL(k_count,  dim3(eb), dim3(256), 0, stream, ei, deg);
    hipLaunchKernelGGL(k_deginv, dim3(rb), dim3(256), 0, stream, deg, dinv, invdeg);
    hipLaunchKernelGGL(k_scan1,  dim3(nb1024), dim3(1024), 0, stream, deg, rp, part);
    hipLaunchKernelGGL(k_scan2,  dim3(1), dim3(1), 0, stream, part, nb1024, rp);
    hipLaunchKernelGGL(k_scan3,  dim3(rb), dim3(256), 0, stream, rp, part);
    hipMemcpyAsync(cursor, rp, (size_t)NN * 4, hipMemcpyDeviceToDevice, stream);
    hipLaunchKernelGGL(k_fill,   dim3(eb), dim3(256), 0, stream, ei, dinv, cursor, cs, nrm);

    // ---- feature path ----
    hipLaunchKernelGGL(k_branch_mfma, dim3(rb128, 4), dim3(256), 0, stream,
        des, twt, pre_x, x, W_des, b_des, W_text, b_text, W_tw, b_tw, W_tr, b_tr, hA);
    hipLaunchKernelGGL(k_small_branch, dim3((NN * 64 + 255) / 256), dim3(256), 0, stream,
        nprop, ncat, W_prop, b_prop, W_cat, b_cat, hA);

    // h1 = lrelu(hA @ W_in^T + b_in) -> hB
    hipLaunchKernelGGL((k_hgemm<true, true>),   dim3(rb128, 6), dim3(256), 0, stream,
        hA, W_in, b_in, hB, HD);
    // hW1 = hB @ W_c1^T -> hC
    hipLaunchKernelGGL((k_hgemm<false, false>), dim3(rb128, 6), dim3(256), 0, stream,
        hB, W_c1, nullptr, hC, HD);
    hipLaunchKernelGGL(k_agg, dim3(NN), dim3(192), 0, stream, hC, rp, cs, nrm, invdeg, b_c1, hA);
    // hW2 = hA @ W_c2^T -> hB
    hipLaunchKernelGGL((k_hgemm<false, false>), dim3(rb128, 6), dim3(256), 0, stream,
        hA, W_c2, nullptr, hB, HD);
    hipLaunchKernelGGL(k_agg, dim3(NN), dim3(192), 0, stream, hB, rp, cs, nrm, invdeg, b_c2, hC);

    // em = lrelu(hC @ W_o1^T + b_o1) -> em [N,96]
    hipLaunchKernelGGL((k_hgemm<true, true>),   dim3(rb128, 3), dim3(256), 0, stream,
        hC, W_o1, b_o1, em, 96);
    // out = em @ W_o2^T + b_o2
    hipLaunchKernelGGL(k_o2, dim3(rb), dim3(256), 0, stream, em, W_o2, b_o2, outp);
}

// Round 3
// 472.059 us; speedup vs baseline: 3.2446x; 1.5324x over previous
//
#include <hip/hip_runtime.h>

#define NN 50000
#define EE 800000
#define LMD 768
#define HD 192
#define SLOPE 0.01f

typedef short bf16x8 __attribute__((ext_vector_type(8)));
typedef float f32x4 __attribute__((ext_vector_type(4)));
typedef unsigned short u16;

__device__ __forceinline__ float lrelu(float v){ return v > 0.f ? v : SLOPE * v; }

// fp32 -> bf16 round-to-nearest-even
__device__ __forceinline__ u16 f2bf(float f){
    unsigned u = __float_as_uint(f);
    u += 0x7FFF + ((u >> 16) & 1u);
    return (u16)(u >> 16);
}
__device__ __forceinline__ float bf2f(u16 v){
    return __uint_as_float(((unsigned)v) << 16);
}

// ================= weight prep: fp32 -> bf16, swizzled layouts =================
// branch W (m 0..3, [32][768]): per-half: dst = m*24576 + h*12288 + c*384 + ((gl^(c&7))<<3) + (kk&7)
//   h = k>=384, kk = k - h*384, gl = kk>>3
// hidden W (m 4..6, [192][192]): dst = 98304 + (m-4)*36864 + win*12288 + c*64 + ((g^(c&7))<<3) + (kk&7)
//   win = k>>6, kk = k&63, g = kk>>3
// o1 W (m 7, [96][192]): dst = 208896 + win*6144 + c*64 + ((g^(c&7))<<3) + (kk&7)
__global__ __launch_bounds__(256) void k_prep(
    const float* __restrict__ W0, const float* __restrict__ W1,
    const float* __restrict__ W2, const float* __restrict__ W3,
    const float* __restrict__ Win, const float* __restrict__ Wc1,
    const float* __restrict__ Wc2, const float* __restrict__ Wo1,
    u16* __restrict__ out)
{
    int m = blockIdx.y;
    int idx = blockIdx.x * 256 + threadIdx.x;
    const float* src; int nelem;
    switch (m) {
      case 0: src = W0;  nelem = 32*768; break;
      case 1: src = W1;  nelem = 32*768; break;
      case 2: src = W2;  nelem = 32*768; break;
      case 3: src = W3;  nelem = 32*768; break;
      case 4: src = Win; nelem = 192*192; break;
      case 5: src = Wc1; nelem = 192*192; break;
      case 6: src = Wc2; nelem = 192*192; break;
      default: src = Wo1; nelem = 96*192; break;
    }
    if (idx >= nelem) return;
    u16 v = f2bf(src[idx]);
    size_t dst;
    if (m < 4) {
        int c = idx / 768, k = idx - c * 768;
        int h = (k >= 384) ? 1 : 0;
        int kk = k - h * 384;
        int gl = kk >> 3;
        dst = (size_t)m * 24576 + h * 12288 + c * 384 + ((gl ^ (c & 7)) << 3) + (kk & 7);
    } else if (m < 7) {
        int c = idx / 192, k = idx - c * 192;
        int win = k >> 6, kk = k & 63, g = kk >> 3;
        dst = 98304 + (size_t)(m - 4) * 36864 + win * 12288 + c * 64 + ((g ^ (c & 7)) << 3) + (kk & 7);
    } else {
        int c = idx / 192, k = idx - c * 192;
        int win = k >> 6, kk = k & 63, g = kk >> 3;
        dst = 208896 + (size_t)win * 6144 + c * 64 + ((g ^ (c & 7)) << 3) + (kk & 7);
    }
    out[dst] = v;
}

// ================= big branches: [N,768] -> bf16 h cols, direct-A MFMA =================
// BM=64 (4 waves x 16 rows), BN=32, no A LDS; W staged per-half (24 KB)
__global__ __launch_bounds__(256) void k_branch(
    const float* __restrict__ des, const float* __restrict__ twt,
    const float* __restrict__ prex, const float* __restrict__ xx,
    const u16* __restrict__ Wp,
    const float* __restrict__ bd, const float* __restrict__ btx,
    const float* __restrict__ btw, const float* __restrict__ btr,
    u16* __restrict__ h)
{
    __shared__ u16 Bs[12288];          // 32 cols x 48 chunks x 8 u16 = 24 KB
    const int br = blockIdx.y;
    const float* A; const float* bias; int colBase;
    switch (br) {
      case 0:  A = des;  bias = bd;  colBase = 64;  break;
      case 1:  A = twt;  bias = btx; colBase = 96;  break;
      case 2:  A = prex; bias = btw; colBase = 128; break;
      default: A = xx;   bias = btr; colBase = 160; break;
    }
    const u16* Wb = Wp + br * 24576;

    const int t = threadIdx.x, w = t >> 6, l = t & 63;
    const int hi = l >> 4;
    const int rowBase = blockIdx.x * 64;
    int row = rowBase + w * 16 + (l & 15);
    int rowc = row < NN ? row : NN - 1;
    const float4* ap = reinterpret_cast<const float4*>(A + (size_t)rowc * LMD + hi * 8);

    f32x4 acc[2] = {};
    float4 pa0 = ap[0], pa1 = ap[1];

    #pragma unroll
    for (int half = 0; half < 2; ++half) {
        __syncthreads();
        const u16* src = Wb + half * 12288;
        #pragma unroll
        for (int i = 0; i < 6; ++i) {
            int slot = i * 256 + t;
            *reinterpret_cast<uint4*>(Bs + slot * 8) =
                *reinterpret_cast<const uint4*>(src + slot * 8);
        }
        __syncthreads();

        #pragma unroll
        for (int s = 0; s < 12; ++s) {
            const int sg = half * 12 + s;
            float4 na0 = pa0, na1 = pa1;
            if (sg < 23) { na0 = ap[(sg + 1) * 8]; na1 = ap[(sg + 1) * 8 + 1]; }

            bf16x8 af;
            af[0] = (short)f2bf(pa0.x); af[1] = (short)f2bf(pa0.y);
            af[2] = (short)f2bf(pa0.z); af[3] = (short)f2bf(pa0.w);
            af[4] = (short)f2bf(pa1.x); af[5] = (short)f2bf(pa1.y);
            af[6] = (short)f2bf(pa1.z); af[7] = (short)f2bf(pa1.w);

            #pragma unroll
            for (int cb = 0; cb < 2; ++cb) {
                int c = cb * 16 + (l & 15);
                int lc = (s * 4 + hi) ^ (c & 7);
                bf16x8 bf = *reinterpret_cast<const bf16x8*>(Bs + c * 384 + lc * 8);
                acc[cb] = __builtin_amdgcn_mfma_f32_16x16x32_bf16(af, bf, acc[cb], 0, 0, 0);
            }
            pa0 = na0; pa1 = na1;
        }
    }

    // C/D: col = lane&15, row = hi*4 + reg
    #pragma unroll
    for (int cb = 0; cb < 2; ++cb) {
        int cl = cb * 16 + (l & 15);
        float bv = bias[cl];
        #pragma unroll
        for (int rg = 0; rg < 4; ++rg) {
            int r = rowBase + w * 16 + hi * 4 + rg;
            if (r < NN)
                h[(size_t)r * HD + colBase + cl] = f2bf(lrelu(acc[cb][rg] + bv));
        }
    }
}

// ================= hidden GEMM: bf16 [N,192] @ W^T -> bf16/f32 [N,OC] =================
// BM=64 (4 waves x 16 rows), BN=OC, A direct-from-global, W staged per 64-k window
template<int OC, bool BIAS, bool LRELU, bool OUTF32>
__global__ __launch_bounds__(256) void k_hgemm(
    const u16* __restrict__ A, const u16* __restrict__ Wp,
    const float* __restrict__ bias, void* __restrict__ outv)
{
    __shared__ u16 Bs[OC * 64];
    const int t = threadIdx.x, w = t >> 6, l = t & 63;
    const int hi = l >> 4;
    const int rowBase = blockIdx.x * 64;
    int row = rowBase + w * 16 + (l & 15);
    int rowc = row < NN ? row : NN - 1;
    const u16* ap = A + (size_t)rowc * HD + hi * 8;

    f32x4 acc[OC / 16] = {};

    #pragma unroll
    for (int win = 0; win < 3; ++win) {
        __syncthreads();
        const u16* src = Wp + win * OC * 64;
        #pragma unroll
        for (int i = 0; i < OC * 8 / 256; ++i) {
            int slot = i * 256 + t;
            *reinterpret_cast<uint4*>(Bs + slot * 8) =
                *reinterpret_cast<const uint4*>(src + slot * 8);
        }
        __syncthreads();

        #pragma unroll
        for (int s2 = 0; s2 < 2; ++s2) {
            int sg = win * 2 + s2;
            bf16x8 af = *reinterpret_cast<const bf16x8*>(ap + sg * 32);
            #pragma unroll
            for (int cb = 0; cb < OC / 16; ++cb) {
                int c = cb * 16 + (l & 15);
                int lc = (s2 * 4 + hi) ^ (c & 7);
                bf16x8 bf = *reinterpret_cast<const bf16x8*>(Bs + c * 64 + lc * 8);
                acc[cb] = __builtin_amdgcn_mfma_f32_16x16x32_bf16(af, bf, acc[cb], 0, 0, 0);
            }
        }
    }

    #pragma unroll
    for (int cb = 0; cb < OC / 16; ++cb) {
        int cl = cb * 16 + (l & 15);
        float bv = BIAS ? bias[cl] : 0.f;
        #pragma unroll
        for (int rg = 0; rg < 4; ++rg) {
            int r = rowBase + w * 16 + hi * 4 + rg;
            if (r < NN) {
                float v = acc[cb][rg] + bv;
                if (LRELU) v = lrelu(v);
                if (OUTF32) ((float*)outv)[(size_t)r * OC + cl] = v;
                else        ((u16*)outv)[(size_t)r * OC + cl] = f2bf(v);
            }
        }
    }
}

// ================= small branches: cols 0..63 =================
__global__ __launch_bounds__(256) void k_small_branch(
    const float* __restrict__ nprop, const float* __restrict__ ncat,
    const float* __restrict__ Wp, const float* __restrict__ bp,
    const float* __restrict__ Wc, const float* __restrict__ bc,
    u16* __restrict__ h)
{
    int idx = blockIdx.x * 256 + threadIdx.x;
    if (idx >= NN * 64) return;
    int row = idx >> 6, c = idx & 63;
    float acc;
    if (c < 32) {
        acc = bp[c];
        #pragma unroll
        for (int k = 0; k < 5; ++k) acc += nprop[row * 5 + k] * Wp[c * 5 + k];
    } else {
        int cc = c - 32;
        acc = bc[cc] + ncat[row] * Wc[cc];
    }
    h[(size_t)row * HD + c] = f2bf(lrelu(acc));
}

// ================= graph structure =================
__global__ void k_count(const int* __restrict__ ei, int* __restrict__ deg)
{
    int e = blockIdx.x * 256 + threadIdx.x;
    if (e < EE) atomicAdd(&deg[ei[EE + e]], 1);
}

__global__ void k_deginv(const int* __restrict__ deg, float* __restrict__ dinv, float* __restrict__ invdeg)
{
    int v = blockIdx.x * 256 + threadIdx.x;
    if (v < NN) {
        float d = (float)(deg[v] + 1);
        dinv[v] = rsqrtf(d);
        invdeg[v] = 1.0f / d;
    }
}

__global__ __launch_bounds__(1024) void k_scan1(const int* __restrict__ deg, int* __restrict__ rp, int* __restrict__ part)
{
    __shared__ int sh[1024];
    int tid = threadIdx.x, i = blockIdx.x * 1024 + tid;
    int x = (i < NN) ? deg[i] : 0;
    sh[tid] = x;
    __syncthreads();
    for (int off = 1; off < 1024; off <<= 1) {
        int y = (tid >= off) ? sh[tid - off] : 0;
        __syncthreads();
        sh[tid] += y;
        __syncthreads();
    }
    if (i < NN) rp[i] = sh[tid] - x;       // exclusive
    if (tid == 1023) part[blockIdx.x] = sh[tid];
}

__global__ void k_scan2(int* part, int nb, int* rp)
{
    if (threadIdx.x == 0 && blockIdx.x == 0) {
        int run = 0;
        for (int b = 0; b < nb; ++b) { int t = part[b]; part[b] = run; run += t; }
        rp[NN] = run;
    }
}

__global__ void k_scan3(int* rp, const int* __restrict__ part)
{
    int i = blockIdx.x * 256 + threadIdx.x;
    if (i < NN) rp[i] += part[i >> 10];
}

__global__ void k_fill(const int* __restrict__ ei, const float* __restrict__ dinv,
                       int* __restrict__ cursor, int* __restrict__ cs, float* __restrict__ nrm)
{
    int e = blockIdx.x * 256 + threadIdx.x;
    if (e >= EE) return;
    int s = ei[e], d = ei[EE + e];
    int pos = atomicAdd(&cursor[d], 1);
    cs[pos] = s;
    nrm[pos] = dinv[s] * dinv[d];
}

// ================= GCN aggregation (bf16 gather, fp32 accum, bf16 out) =================
__global__ __launch_bounds__(192) void k_agg(const u16* __restrict__ hW,
    const int* __restrict__ rp, const int* __restrict__ cs, const float* __restrict__ nrm,
    const float* __restrict__ invdeg, const float* __restrict__ bias, u16* __restrict__ out)
{
    int v = blockIdx.x;
    int f = threadIdx.x;
    int s0 = rp[v], s1 = rp[v + 1];
    float acc = bf2f(hW[(size_t)v * HD + f]) * invdeg[v] + bias[f];
    int i = s0;
    for (; i + 4 <= s1; i += 4) {
        int c0 = cs[i], c1 = cs[i + 1], c2 = cs[i + 2], c3 = cs[i + 3];
        float n0 = nrm[i], n1 = nrm[i + 1], n2 = nrm[i + 2], n3 = nrm[i + 3];
        float v0 = bf2f(hW[(size_t)c0 * HD + f]);
        float v1 = bf2f(hW[(size_t)c1 * HD + f]);
        float v2 = bf2f(hW[(size_t)c2 * HD + f]);
        float v3 = bf2f(hW[(size_t)c3 * HD + f]);
        acc += v0 * n0; acc += v1 * n1; acc += v2 * n2; acc += v3 * n3;
    }
    for (; i < s1; ++i)
        acc += bf2f(hW[(size_t)cs[i] * HD + f]) * nrm[i];
    out[(size_t)v * HD + f] = f2bf(acc);
}

// ================= final [N,96] fp32 -> [N,2] =================
__global__ __launch_bounds__(256) void k_o2(const float* __restrict__ em,
    const float* __restrict__ W, const float* __restrict__ b, float* __restrict__ out)
{
    int idx = blockIdx.x * 256 + threadIdx.x;
    int row = idx >> 2, q = idx & 3;
    if (row >= NN) return;
    const float4* e4 = reinterpret_cast<const float4*>(em + (size_t)row * 96) + q * 6;
    const float4* w0 = reinterpret_cast<const float4*>(W) + q * 6;
    const float4* w1 = reinterpret_cast<const float4*>(W + 96) + q * 6;
    float a0 = 0.f, a1 = 0.f;
    #pragma unroll
    for (int k = 0; k < 6; ++k) {
        float4 v = e4[k], x0 = w0[k], x1 = w1[k];
        a0 += v.x * x0.x + v.y * x0.y + v.z * x0.z + v.w * x0.w;
        a1 += v.x * x1.x + v.y * x1.y + v.z * x1.z + v.w * x1.w;
    }
    a0 += __shfl_xor(a0, 1); a0 += __shfl_xor(a0, 2);
    a1 += __shfl_xor(a1, 1); a1 += __shfl_xor(a1, 2);
    if (q == 0) {
        out[row * 2 + 0] = a0 + b[0];
        out[row * 2 + 1] = a1 + b[1];
    }
}

extern "C" void kernel_launch(void* const* d_in, const int* in_sizes, int n_in,
                              void* d_out, int out_size, void* d_ws, size_t ws_size,
                              hipStream_t stream)
{
    const float* pre_x = (const float*)d_in[0];
    const float* x     = (const float*)d_in[1];
    const int*   ei    = (const int*)d_in[2];
    const float* nprop = (const float*)d_in[4];
    const float* ncat  = (const float*)d_in[5];
    const float* des   = (const float*)d_in[6];
    const float* twt   = (const float*)d_in[7];
    const float* W_des  = (const float*)d_in[8],  *b_des  = (const float*)d_in[9];
    const float* W_tw   = (const float*)d_in[10], *b_tw   = (const float*)d_in[11];
    const float* W_tr   = (const float*)d_in[12], *b_tr   = (const float*)d_in[13];
    const float* W_prop = (const float*)d_in[14], *b_prop = (const float*)d_in[15];
    const float* W_cat  = (const float*)d_in[16], *b_cat  = (const float*)d_in[17];
    const float* W_text = (const float*)d_in[18], *b_text = (const float*)d_in[19];
    const float* W_in   = (const float*)d_in[20], *b_in   = (const float*)d_in[21];
    const float* W_c1   = (const float*)d_in[22], *b_c1   = (const float*)d_in[23];
    const float* W_c2   = (const float*)d_in[24], *b_c2   = (const float*)d_in[25];
    const float* W_o1   = (const float*)d_in[26], *b_o1   = (const float*)d_in[27];
    const float* W_o2   = (const float*)d_in[28], *b_o2   = (const float*)d_in[29];

    char* base = (char*)d_ws;
    size_t off = 0;
    auto alloc = [&](size_t bytes) -> char* {
        char* p = base + off;
        off = (off + bytes + 255) & ~(size_t)255;
        return p;
    };
    u16*   hA     = (u16*)alloc((size_t)NN * HD * 2);
    u16*   hB     = (u16*)alloc((size_t)NN * HD * 2);
    u16*   hC     = (u16*)alloc((size_t)NN * HD * 2);
    u16*   Wprep  = (u16*)alloc((size_t)227328 * 2);
    float* dinv   = (float*)alloc((size_t)NN * 4);
    float* invdeg = (float*)alloc((size_t)NN * 4);
    int*   deg    = (int*)alloc((size_t)NN * 4);
    int*   rp     = (int*)alloc((size_t)(NN + 1) * 4);
    int*   cursor = (int*)alloc((size_t)NN * 4);
    int*   part   = (int*)alloc(64 * 4);
    int*   cs     = (int*)alloc((size_t)EE * 4);
    float* nrm    = (float*)alloc((size_t)EE * 4);
    (void)ws_size; (void)in_sizes; (void)n_in; (void)out_size;

    float* outp = (float*)d_out;            // [N,2]
    float* em   = outp + (size_t)NN * 2;    // [N,96] fp32 (output)

    const int rb    = (NN + 255) / 256;     // 196
    const int rb64  = (NN + 63) / 64;       // 782
    const int eb    = (EE + 255) / 256;     // 3125
    const int nb1024 = (NN + 1023) / 1024;  // 49

    // ---- weight prep + graph structure ----
    hipMemsetAsync(deg, 0, (size_t)NN * 4, stream);
    hipLaunchKernelGGL(k_prep, dim3(144, 8), dim3(256), 0, stream,
        W_des, W_text, W_tw, W_tr, W_in, W_c1, W_c2, W_o1, Wprep);
    hipLaunchKernelGGL(k_count,  dim3(eb), dim3(256), 0, stream, ei, deg);
    hipLaunchKernelGGL(k_deginv, dim3(rb), dim3(256), 0, stream, deg, dinv, invdeg);
    hipLaunchKernelGGL(k_scan1,  dim3(nb1024), dim3(1024), 0, stream, deg, rp, part);
    hipLaunchKernelGGL(k_scan2,  dim3(1), dim3(1), 0, stream, part, nb1024, rp);
    hipLaunchKernelGGL(k_scan3,  dim3(rb), dim3(256), 0, stream, rp, part);
    hipMemcpyAsync(cursor, rp, (size_t)NN * 4, hipMemcpyDeviceToDevice, stream);
    hipLaunchKernelGGL(k_fill,   dim3(eb), dim3(256), 0, stream, ei, dinv, cursor, cs, nrm);

    // ---- feature path ----
    hipLaunchKernelGGL(k_branch, dim3(rb64, 4), dim3(256), 0, stream,
        des, twt, pre_x, x, Wprep, b_des, b_text, b_tw, b_tr, hA);
    hipLaunchKernelGGL(k_small_branch, dim3((NN * 64 + 255) / 256), dim3(256), 0, stream,
        nprop, ncat, W_prop, b_prop, W_cat, b_cat, hA);

    // h1 = lrelu(hA @ W_in^T + b_in) -> hB (bf16)
    hipLaunchKernelGGL((k_hgemm<192, true, true, false>),   dim3(rb64), dim3(256), 0, stream,
        hA, Wprep + 98304, b_in, hB);
    // hW1 = hB @ W_c1^T -> hC (bf16)
    hipLaunchKernelGGL((k_hgemm<192, false, false, false>), dim3(rb64), dim3(256), 0, stream,
        hB, Wprep + 98304 + 36864, nullptr, hC);
    hipLaunchKernelGGL(k_agg, dim3(NN), dim3(192), 0, stream, hC, rp, cs, nrm, invdeg, b_c1, hA);
    // hW2 = hA @ W_c2^T -> hB (bf16)
    hipLaunchKernelGGL((k_hgemm<192, false, false, false>), dim3(rb64), dim3(256), 0, stream,
        hA, Wprep + 98304 + 2 * 36864, nullptr, hB);
    hipLaunchKernelGGL(k_agg, dim3(NN), dim3(192), 0, stream, hB, rp, cs, nrm, invdeg, b_c2, hC);

    // em = lrelu(hC @ W_o1^T + b_o1) -> em fp32 [N,96]
    hipLaunchKernelGGL((k_hgemm<96, true, true, true>),     dim3(rb64), dim3(256), 0, stream,
        hC, Wprep + 208896, b_o1, em);
    // out = em @ W_o2^T + b_o2
    hipLaunchKernelGGL(k_o2, dim3((NN * 4 + 255) / 256), dim3(256), 0, stream, em, W_o2, b_o2, outp);
}

// Round 4
// 440.516 us; speedup vs baseline: 3.4769x; 1.0716x over previous
//
#include <hip/hip_runtime.h>

#define NN 50000
#define EE 800000
#define LMD 768
#define HD 192
#define SLOPE 0.01f

typedef short bf16x8 __attribute__((ext_vector_type(8)));
typedef float f32x4 __attribute__((ext_vector_type(4)));
typedef unsigned short u16;

__device__ __forceinline__ float lrelu(float v){ return v > 0.f ? v : SLOPE * v; }

// fp32 -> bf16 round-to-nearest-even
__device__ __forceinline__ u16 f2bf(float f){
    unsigned u = __float_as_uint(f);
    u += 0x7FFF + ((u >> 16) & 1u);
    return (u16)(u >> 16);
}
__device__ __forceinline__ float bf2f(u16 v){
    return __uint_as_float(((unsigned)v) << 16);
}

// ================= weight prep: fp32 -> bf16 frag-linear =================
// Fragment convention (16x16x32 mfma): lane = hi*16 + lr; A/B elem: row/col = lr,
// k = sg*32 + hi*8 + j (j=0..7). Frag storage: frag_id*512 + lane*8 + j.
// branch m=0..3 ([32][768]):  dst = m*24576 + (sg*2+cb)*512 + lane*8 + j
// hidden m=4..6 ([192][192]): dst = 98304 + (m-4)*36864 + (sg*12+cb)*512 + lane*8 + j
// o1     m=7   ([96][192]):   dst = 208896 + (sg*6+cb)*512 + lane*8 + j
__global__ __launch_bounds__(256) void k_prep(
    const float* __restrict__ W0, const float* __restrict__ W1,
    const float* __restrict__ W2, const float* __restrict__ W3,
    const float* __restrict__ Win, const float* __restrict__ Wc1,
    const float* __restrict__ Wc2, const float* __restrict__ Wo1,
    u16* __restrict__ out)
{
    int m = blockIdx.y;
    int idx = blockIdx.x * 256 + threadIdx.x;
    const float* src; int nelem; int K;
    switch (m) {
      case 0: src = W0;  nelem = 32*768;  K = 768; break;
      case 1: src = W1;  nelem = 32*768;  K = 768; break;
      case 2: src = W2;  nelem = 32*768;  K = 768; break;
      case 3: src = W3;  nelem = 32*768;  K = 768; break;
      case 4: src = Win; nelem = 192*192; K = 192; break;
      case 5: src = Wc1; nelem = 192*192; K = 192; break;
      case 6: src = Wc2; nelem = 192*192; K = 192; break;
      default: src = Wo1; nelem = 96*192; K = 192; break;
    }
    if (idx >= nelem) return;
    u16 v = f2bf(src[idx]);
    int c = idx / K, k = idx - c * K;
    int cb = c >> 4, lr = c & 15;
    int sg = k >> 5, kk = k & 31, hi = kk >> 3, j = kk & 7;
    int lane = hi * 16 + lr;
    size_t dst;
    if (m < 4)      dst = (size_t)m * 24576 + (sg * 2 + cb) * 512 + lane * 8 + j;
    else if (m < 7) dst = 98304 + (size_t)(m - 4) * 36864 + (sg * 12 + cb) * 512 + lane * 8 + j;
    else            dst = 208896 + (size_t)(sg * 6 + cb) * 512 + lane * 8 + j;
    out[dst] = v;
}

// ================= big branches: [N,768] fp32 -> bf16 h cols; no LDS, no barriers =================
__global__ __launch_bounds__(256) void k_branch(
    const float* __restrict__ des, const float* __restrict__ twt,
    const float* __restrict__ prex, const float* __restrict__ xx,
    const u16* __restrict__ Wf,
    const float* __restrict__ bd, const float* __restrict__ btx,
    const float* __restrict__ btw, const float* __restrict__ btr,
    u16* __restrict__ h)
{
    const int br = blockIdx.y;
    const float* A; const float* bias; int colBase;
    switch (br) {
      case 0:  A = des;  bias = bd;  colBase = 64;  break;
      case 1:  A = twt;  bias = btx; colBase = 96;  break;
      case 2:  A = prex; bias = btw; colBase = 128; break;
      default: A = xx;   bias = btr; colBase = 160; break;
    }
    const u16* Wb = Wf + br * 24576;

    const int t = threadIdx.x, w = t >> 6, l = t & 63;
    const int hi = l >> 4, lr = l & 15;
    const int rowBase = blockIdx.x * 64;
    int row = rowBase + w * 16 + lr;
    int rowc = row < NN ? row : NN - 1;
    const float4* ap = reinterpret_cast<const float4*>(A) + (size_t)rowc * 192;
    const int fo = hi * 2;

    f32x4 acc[2] = {};
    float4 buf[4][2];
    #pragma unroll
    for (int s = 0; s < 4; ++s) {
        buf[s][0] = ap[s * 8 + fo];
        buf[s][1] = ap[s * 8 + fo + 1];
    }

    #pragma unroll
    for (int sg = 0; sg < 24; ++sg) {
        float4 a0 = buf[sg & 3][0], a1 = buf[sg & 3][1];
        if (sg + 4 < 24) {
            buf[sg & 3][0] = ap[(sg + 4) * 8 + fo];
            buf[sg & 3][1] = ap[(sg + 4) * 8 + fo + 1];
        }
        bf16x8 af;
        af[0] = (short)f2bf(a0.x); af[1] = (short)f2bf(a0.y);
        af[2] = (short)f2bf(a0.z); af[3] = (short)f2bf(a0.w);
        af[4] = (short)f2bf(a1.x); af[5] = (short)f2bf(a1.y);
        af[6] = (short)f2bf(a1.z); af[7] = (short)f2bf(a1.w);
        #pragma unroll
        for (int cb = 0; cb < 2; ++cb) {
            bf16x8 bf = *reinterpret_cast<const bf16x8*>(Wb + (sg * 2 + cb) * 512 + l * 8);
            acc[cb] = __builtin_amdgcn_mfma_f32_16x16x32_bf16(af, bf, acc[cb], 0, 0, 0);
        }
    }

    // C/D: col = lr, row = hi*4 + reg
    #pragma unroll
    for (int cb = 0; cb < 2; ++cb) {
        int cl = cb * 16 + lr;
        float bv = bias[cl];
        #pragma unroll
        for (int rg = 0; rg < 4; ++rg) {
            int r = rowBase + w * 16 + hi * 4 + rg;
            if (r < NN)
                h[(size_t)r * HD + colBase + cl] = f2bf(lrelu(acc[cb][rg] + bv));
        }
    }
}

// ================= hidden GEMM: bf16 [N,192] @ W^T -> bf16 [N,192]; no LDS =================
template<bool BIAS, bool LRELU>
__global__ __launch_bounds__(256) void k_hgemm(
    const u16* __restrict__ A, const u16* __restrict__ Wf,
    const float* __restrict__ bias, u16* __restrict__ out)
{
    const int t = threadIdx.x, w = t >> 6, l = t & 63;
    const int hi = l >> 4, lr = l & 15;
    const int rowBase = blockIdx.x * 64;
    int row = rowBase + w * 16 + lr;
    int rowc = row < NN ? row : NN - 1;
    const u16* ap = A + (size_t)rowc * HD;

    bf16x8 afr[6];
    #pragma unroll
    for (int sg = 0; sg < 6; ++sg)
        afr[sg] = *reinterpret_cast<const bf16x8*>(ap + sg * 32 + hi * 8);

    f32x4 acc[12] = {};
    #pragma unroll
    for (int sg = 0; sg < 6; ++sg) {
        #pragma unroll
        for (int cb = 0; cb < 12; ++cb) {
            bf16x8 bf = *reinterpret_cast<const bf16x8*>(Wf + (sg * 12 + cb) * 512 + l * 8);
            acc[cb] = __builtin_amdgcn_mfma_f32_16x16x32_bf16(afr[sg], bf, acc[cb], 0, 0, 0);
        }
    }

    #pragma unroll
    for (int cb = 0; cb < 12; ++cb) {
        int cl = cb * 16 + lr;
        float bv = BIAS ? bias[cl] : 0.f;
        #pragma unroll
        for (int rg = 0; rg < 4; ++rg) {
            int r = rowBase + w * 16 + hi * 4 + rg;
            if (r < NN) {
                float v = acc[cb][rg] + bv;
                if (LRELU) v = lrelu(v);
                out[(size_t)r * HD + cl] = f2bf(v);
            }
        }
    }
}

// ================= final: em = lrelu(hC @ Wo1^T + b1) [N,96] fp32 + out = em @ Wo2^T + b2 =================
__global__ __launch_bounds__(256) void k_final(
    const u16* __restrict__ A, const u16* __restrict__ Wf,
    const float* __restrict__ b1, const float* __restrict__ W2,
    const float* __restrict__ b2, float* __restrict__ em, float* __restrict__ out)
{
    const int t = threadIdx.x, w = t >> 6, l = t & 63;
    const int hi = l >> 4, lr = l & 15;
    const int rowBase = blockIdx.x * 64;
    int row = rowBase + w * 16 + lr;
    int rowc = row < NN ? row : NN - 1;
    const u16* ap = A + (size_t)rowc * HD;

    bf16x8 afr[6];
    #pragma unroll
    for (int sg = 0; sg < 6; ++sg)
        afr[sg] = *reinterpret_cast<const bf16x8*>(ap + sg * 32 + hi * 8);

    f32x4 acc[6] = {};
    #pragma unroll
    for (int sg = 0; sg < 6; ++sg) {
        #pragma unroll
        for (int cb = 0; cb < 6; ++cb) {
            bf16x8 bf = *reinterpret_cast<const bf16x8*>(Wf + (sg * 6 + cb) * 512 + l * 8);
            acc[cb] = __builtin_amdgcn_mfma_f32_16x16x32_bf16(afr[sg], bf, acc[cb], 0, 0, 0);
        }
    }

    float w2v[2][6], bv[6];
    #pragma unroll
    for (int cb = 0; cb < 6; ++cb) {
        bv[cb] = b1[cb * 16 + lr];
        w2v[0][cb] = W2[cb * 16 + lr];
        w2v[1][cb] = W2[96 + cb * 16 + lr];
    }

    #pragma unroll
    for (int rg = 0; rg < 4; ++rg) {
        int r = rowBase + w * 16 + hi * 4 + rg;
        float o0 = 0.f, o1 = 0.f;
        #pragma unroll
        for (int cb = 0; cb < 6; ++cb) {
            float v = lrelu(acc[cb][rg] + bv[cb]);
            if (r < NN) em[(size_t)r * 96 + cb * 16 + lr] = v;
            o0 += v * w2v[0][cb];
            o1 += v * w2v[1][cb];
        }
        #pragma unroll
        for (int d = 1; d < 16; d <<= 1) {
            o0 += __shfl_xor(o0, d);
            o1 += __shfl_xor(o1, d);
        }
        if (lr == 0 && r < NN) {
            out[r * 2 + 0] = o0 + b2[0];
            out[r * 2 + 1] = o1 + b2[1];
        }
    }
}

// ================= small branches: cols 0..63 =================
__global__ __launch_bounds__(256) void k_small_branch(
    const float* __restrict__ nprop, const float* __restrict__ ncat,
    const float* __restrict__ Wp, const float* __restrict__ bp,
    const float* __restrict__ Wc, const float* __restrict__ bc,
    u16* __restrict__ h)
{
    int idx = blockIdx.x * 256 + threadIdx.x;
    if (idx >= NN * 64) return;
    int row = idx >> 6, c = idx & 63;
    float acc;
    if (c < 32) {
        acc = bp[c];
        #pragma unroll
        for (int k = 0; k < 5; ++k) acc += nprop[row * 5 + k] * Wp[c * 5 + k];
    } else {
        int cc = c - 32;
        acc = bc[cc] + ncat[row] * Wc[cc];
    }
    h[(size_t)row * HD + c] = f2bf(lrelu(acc));
}

// ================= graph structure =================
__global__ void k_count(const int* __restrict__ ei, int* __restrict__ deg)
{
    int e = blockIdx.x * 256 + threadIdx.x;
    if (e < EE) atomicAdd(&deg[ei[EE + e]], 1);
}

__global__ void k_deginv(const int* __restrict__ deg, float* __restrict__ dinv, float* __restrict__ invdeg)
{
    int v = blockIdx.x * 256 + threadIdx.x;
    if (v < NN) {
        float d = (float)(deg[v] + 1);
        dinv[v] = rsqrtf(d);
        invdeg[v] = 1.0f / d;
    }
}

__global__ __launch_bounds__(1024) void k_scan1(const int* __restrict__ deg, int* __restrict__ rp, int* __restrict__ part)
{
    __shared__ int sh[1024];
    int tid = threadIdx.x, i = blockIdx.x * 1024 + tid;
    int x = (i < NN) ? deg[i] : 0;
    sh[tid] = x;
    __syncthreads();
    for (int off = 1; off < 1024; off <<= 1) {
        int y = (tid >= off) ? sh[tid - off] : 0;
        __syncthreads();
        sh[tid] += y;
        __syncthreads();
    }
    if (i < NN) rp[i] = sh[tid] - x;       // exclusive
    if (tid == 1023) part[blockIdx.x] = sh[tid];
}

__global__ void k_scan2(int* part, int nb, int* rp)
{
    if (threadIdx.x == 0 && blockIdx.x == 0) {
        int run = 0;
        for (int b = 0; b < nb; ++b) { int t = part[b]; part[b] = run; run += t; }
        rp[NN] = run;
    }
}

__global__ void k_scan3(int* rp, const int* __restrict__ part)
{
    int i = blockIdx.x * 256 + threadIdx.x;
    if (i < NN) rp[i] += part[i >> 10];
}

__global__ void k_fill(const int* __restrict__ ei, const float* __restrict__ dinv,
                       int* __restrict__ cursor, int* __restrict__ cs, float* __restrict__ nrm)
{
    int e = blockIdx.x * 256 + threadIdx.x;
    if (e >= EE) return;
    int s = ei[e], d = ei[EE + e];
    int pos = atomicAdd(&cursor[d], 1);
    cs[pos] = s;
    nrm[pos] = dinv[s] * dinv[d];
}

// ================= GCN aggregation: 48 lanes x ushort4, 5 nodes/block =================
__global__ __launch_bounds__(240) void k_agg(const u16* __restrict__ hW,
    const int* __restrict__ rp, const int* __restrict__ cs, const float* __restrict__ nrm,
    const float* __restrict__ invdeg, const float* __restrict__ bias, u16* __restrict__ out)
{
    int v = blockIdx.x * 5 + threadIdx.y;
    int f0 = threadIdx.x * 4;
    int s0 = rp[v], s1 = rp[v + 1];
    float4 bv = *reinterpret_cast<const float4*>(bias + f0);
    ushort4 hv = *reinterpret_cast<const ushort4*>(hW + (size_t)v * HD + f0);
    float idg = invdeg[v];
    float a0 = bf2f(hv.x) * idg + bv.x;
    float a1 = bf2f(hv.y) * idg + bv.y;
    float a2 = bf2f(hv.z) * idg + bv.z;
    float a3 = bf2f(hv.w) * idg + bv.w;
    int i = s0;
    for (; i + 4 <= s1; i += 4) {
        int c0 = cs[i], c1 = cs[i+1], c2 = cs[i+2], c3 = cs[i+3];
        float n0 = nrm[i], n1 = nrm[i+1], n2 = nrm[i+2], n3 = nrm[i+3];
        ushort4 g0 = *reinterpret_cast<const ushort4*>(hW + (size_t)c0 * HD + f0);
        ushort4 g1 = *reinterpret_cast<const ushort4*>(hW + (size_t)c1 * HD + f0);
        ushort4 g2 = *reinterpret_cast<const ushort4*>(hW + (size_t)c2 * HD + f0);
        ushort4 g3 = *reinterpret_cast<const ushort4*>(hW + (size_t)c3 * HD + f0);
        a0 += bf2f(g0.x) * n0; a1 += bf2f(g0.y) * n0; a2 += bf2f(g0.z) * n0; a3 += bf2f(g0.w) * n0;
        a0 += bf2f(g1.x) * n1; a1 += bf2f(g1.y) * n1; a2 += bf2f(g1.z) * n1; a3 += bf2f(g1.w) * n1;
        a0 += bf2f(g2.x) * n2; a1 += bf2f(g2.y) * n2; a2 += bf2f(g2.z) * n2; a3 += bf2f(g2.w) * n2;
        a0 += bf2f(g3.x) * n3; a1 += bf2f(g3.y) * n3; a2 += bf2f(g3.z) * n3; a3 += bf2f(g3.w) * n3;
    }
    for (; i < s1; ++i) {
        int c = cs[i]; float n = nrm[i];
        ushort4 g = *reinterpret_cast<const ushort4*>(hW + (size_t)c * HD + f0);
        a0 += bf2f(g.x) * n; a1 += bf2f(g.y) * n; a2 += bf2f(g.z) * n; a3 += bf2f(g.w) * n;
    }
    ushort4 o;
    o.x = f2bf(a0); o.y = f2bf(a1); o.z = f2bf(a2); o.w = f2bf(a3);
    *reinterpret_cast<ushort4*>(out + (size_t)v * HD + f0) = o;
}

extern "C" void kernel_launch(void* const* d_in, const int* in_sizes, int n_in,
                              void* d_out, int out_size, void* d_ws, size_t ws_size,
                              hipStream_t stream)
{
    const float* pre_x = (const float*)d_in[0];
    const float* x     = (const float*)d_in[1];
    const int*   ei    = (const int*)d_in[2];
    const float* nprop = (const float*)d_in[4];
    const float* ncat  = (const float*)d_in[5];
    const float* des   = (const float*)d_in[6];
    const float* twt   = (const float*)d_in[7];
    const float* W_des  = (const float*)d_in[8],  *b_des  = (const float*)d_in[9];
    const float* W_tw   = (const float*)d_in[10], *b_tw   = (const float*)d_in[11];
    const float* W_tr   = (const float*)d_in[12], *b_tr   = (const float*)d_in[13];
    const float* W_prop = (const float*)d_in[14], *b_prop = (const float*)d_in[15];
    const float* W_cat  = (const float*)d_in[16], *b_cat  = (const float*)d_in[17];
    const float* W_text = (const float*)d_in[18], *b_text = (const float*)d_in[19];
    const float* W_in   = (const float*)d_in[20], *b_in   = (const float*)d_in[21];
    const float* W_c1   = (const float*)d_in[22], *b_c1   = (const float*)d_in[23];
    const float* W_c2   = (const float*)d_in[24], *b_c2   = (const float*)d_in[25];
    const float* W_o1   = (const float*)d_in[26], *b_o1   = (const float*)d_in[27];
    const float* W_o2   = (const float*)d_in[28], *b_o2   = (const float*)d_in[29];

    char* base = (char*)d_ws;
    size_t off = 0;
    auto alloc = [&](size_t bytes) -> char* {
        char* p = base + off;
        off = (off + bytes + 255) & ~(size_t)255;
        return p;
    };
    u16*   hA     = (u16*)alloc((size_t)NN * HD * 2);
    u16*   hB     = (u16*)alloc((size_t)NN * HD * 2);
    u16*   hC     = (u16*)alloc((size_t)NN * HD * 2);
    u16*   Wprep  = (u16*)alloc((size_t)227328 * 2);
    float* dinv   = (float*)alloc((size_t)NN * 4);
    float* invdeg = (float*)alloc((size_t)NN * 4);
    int*   deg    = (int*)alloc((size_t)NN * 4);
    int*   rp     = (int*)alloc((size_t)(NN + 1) * 4);
    int*   cursor = (int*)alloc((size_t)NN * 4);
    int*   part   = (int*)alloc(64 * 4);
    int*   cs     = (int*)alloc((size_t)EE * 4);
    float* nrm    = (float*)alloc((size_t)EE * 4);
    (void)ws_size; (void)in_sizes; (void)n_in; (void)out_size;

    float* outp = (float*)d_out;            // [N,2]
    float* em   = outp + (size_t)NN * 2;    // [N,96] fp32 (output)

    const int rb    = (NN + 255) / 256;     // 196
    const int rb64  = (NN + 63) / 64;       // 782
    const int eb    = (EE + 255) / 256;     // 3125
    const int nb1024 = (NN + 1023) / 1024;  // 49

    // ---- weight prep + graph structure ----
    hipMemsetAsync(deg, 0, (size_t)NN * 4, stream);
    hipLaunchKernelGGL(k_prep, dim3(144, 8), dim3(256), 0, stream,
        W_des, W_text, W_tw, W_tr, W_in, W_c1, W_c2, W_o1, Wprep);
    hipLaunchKernelGGL(k_count,  dim3(eb), dim3(256), 0, stream, ei, deg);
    hipLaunchKernelGGL(k_deginv, dim3(rb), dim3(256), 0, stream, deg, dinv, invdeg);
    hipLaunchKernelGGL(k_scan1,  dim3(nb1024), dim3(1024), 0, stream, deg, rp, part);
    hipLaunchKernelGGL(k_scan2,  dim3(1), dim3(1), 0, stream, part, nb1024, rp);
    hipLaunchKernelGGL(k_scan3,  dim3(rb), dim3(256), 0, stream, rp, part);
    hipMemcpyAsync(cursor, rp, (size_t)NN * 4, hipMemcpyDeviceToDevice, stream);
    hipLaunchKernelGGL(k_fill,   dim3(eb), dim3(256), 0, stream, ei, dinv, cursor, cs, nrm);

    // ---- feature path ----
    hipLaunchKernelGGL(k_branch, dim3(rb64, 4), dim3(256), 0, stream,
        des, twt, pre_x, x, Wprep, b_des, b_text, b_tw, b_tr, hA);
    hipLaunchKernelGGL(k_small_branch, dim3((NN * 64 + 255) / 256), dim3(256), 0, stream,
        nprop, ncat, W_prop, b_prop, W_cat, b_cat, hA);

    // h1 = lrelu(hA @ W_in^T + b_in) -> hB
    hipLaunchKernelGGL((k_hgemm<true, true>),   dim3(rb64), dim3(256), 0, stream,
        hA, Wprep + 98304, b_in, hB);
    // hW1 = hB @ W_c1^T -> hC
    hipLaunchKernelGGL((k_hgemm<false, false>), dim3(rb64), dim3(256), 0, stream,
        hB, Wprep + 98304 + 36864, nullptr, hC);
    hipLaunchKernelGGL(k_agg, dim3(NN / 5), dim3(48, 5), 0, stream, hC, rp, cs, nrm, invdeg, b_c1, hA);
    // hW2 = hA @ W_c2^T -> hB
    hipLaunchKernelGGL((k_hgemm<false, false>), dim3(rb64), dim3(256), 0, stream,
        hA, Wprep + 98304 + 2 * 36864, nullptr, hB);
    hipLaunchKernelGGL(k_agg, dim3(NN / 5), dim3(48, 5), 0, stream, hB, rp, cs, nrm, invdeg, b_c2, hC);

    // em + out (fused o1/o2)
    hipLaunchKernelGGL(k_final, dim3(rb64), dim3(256), 0, stream,
        hC, Wprep + 208896, b_o1, W_o2, b_o2, em, outp);
}

// Round 5
// 410.176 us; speedup vs baseline: 3.7341x; 1.0740x over previous
//
#include <hip/hip_runtime.h>

#define NN 50000
#define EE 800000
#define LMD 768
#define HD 192
#define SLOPE 0.01f

typedef short bf16x8 __attribute__((ext_vector_type(8)));
typedef float f32x4 __attribute__((ext_vector_type(4)));
typedef unsigned short u16;

__device__ __forceinline__ float lrelu(float v){ return v > 0.f ? v : SLOPE * v; }

__device__ __forceinline__ u16 f2bf(float f){
    unsigned u = __float_as_uint(f);
    u += 0x7FFF + ((u >> 16) & 1u);
    return (u16)(u >> 16);
}
__device__ __forceinline__ float bf2f(u16 v){
    return __uint_as_float(((unsigned)v) << 16);
}
__device__ __forceinline__ bf16x8 as_bf8(float4 v){
    union { float4 f; bf16x8 b; } u; u.f = v; return u.b;
}

// ================= weight prep: fp32 -> bf16 frag-linear =================
// frag (16x16x32): lane = hi*16 + lr; B elem col=lr, k = sg*32 + hi*8 + j.
// storage: frag_id*512 + lane*8 + j.
// branch m=0..3 ([32][768]):  frag = sg*2+cb        -> m*24576 + frag*512 + lane*8 + j
// hidden m=4..6 ([192][192]): frag = sg*12+cb       -> 98304 + (m-4)*36864 + ...
// o1     m=7   ([96][192]):   frag = sg*6+cb        -> 208896 + ...
__global__ __launch_bounds__(256) void k_prep(
    const float* __restrict__ W0, const float* __restrict__ W1,
    const float* __restrict__ W2, const float* __restrict__ W3,
    const float* __restrict__ Win, const float* __restrict__ Wc1,
    const float* __restrict__ Wc2, const float* __restrict__ Wo1,
    u16* __restrict__ out)
{
    int m = blockIdx.y;
    int idx = blockIdx.x * 256 + threadIdx.x;
    const float* src; int nelem; int K;
    switch (m) {
      case 0: src = W0;  nelem = 32*768;  K = 768; break;
      case 1: src = W1;  nelem = 32*768;  K = 768; break;
      case 2: src = W2;  nelem = 32*768;  K = 768; break;
      case 3: src = W3;  nelem = 32*768;  K = 768; break;
      case 4: src = Win; nelem = 192*192; K = 192; break;
      case 5: src = Wc1; nelem = 192*192; K = 192; break;
      case 6: src = Wc2; nelem = 192*192; K = 192; break;
      default: src = Wo1; nelem = 96*192; K = 192; break;
    }
    if (idx >= nelem) return;
    u16 v = f2bf(src[idx]);
    int c = idx / K, k = idx - c * K;
    int cb = c >> 4, lr = c & 15;
    int sg = k >> 5, kk = k & 31, hi = kk >> 3, j = kk & 7;
    int lane = hi * 16 + lr;
    size_t dst;
    if (m < 4)      dst = (size_t)m * 24576 + (sg * 2 + cb) * 512 + lane * 8 + j;
    else if (m < 7) dst = 98304 + (size_t)(m - 4) * 36864 + (sg * 12 + cb) * 512 + lane * 8 + j;
    else            dst = 208896 + (size_t)(sg * 6 + cb) * 512 + lane * 8 + j;
    out[dst] = v;
}

// ================= big branches: [N,768] fp32 -> bf16 h cols =================
// 256 thr (4 waves), 64 rows/block. B in LDS per K-half; A loaded contiguous,
// converted, ds_write-transposed to per-wave frag buffer. Pinned prefetch.
#define BR_LOAD(R0, R1, c) { \
  _Pragma("unroll") for (int rt = 0; rt < 4; ++rt) { \
    const float* p_ = abase[rt] + (c) * 128; \
    R0[rt] = *(const float4*)p_; R1[rt] = *(const float4*)(p_ + 4); } \
  _Pragma("unroll") for (int rt = 0; rt < 4; ++rt) { \
    asm volatile("" :: "v"(R0[rt].x), "v"(R0[rt].y), "v"(R0[rt].z), "v"(R0[rt].w)); \
    asm volatile("" :: "v"(R1[rt].x), "v"(R1[rt].y), "v"(R1[rt].z), "v"(R1[rt].w)); } }

#define BR_WRITE(R0, R1) { \
  _Pragma("unroll") for (int rt = 0; rt < 4; ++rt) { \
    uint4 pk_; \
    pk_.x = (unsigned)f2bf(R0[rt].x) | ((unsigned)f2bf(R0[rt].y) << 16); \
    pk_.y = (unsigned)f2bf(R0[rt].z) | ((unsigned)f2bf(R0[rt].w) << 16); \
    pk_.z = (unsigned)f2bf(R1[rt].x) | ((unsigned)f2bf(R1[rt].y) << 16); \
    pk_.w = (unsigned)f2bf(R1[rt].z) | ((unsigned)f2bf(R1[rt].w) << 16); \
    *(uint4*)(Asg + wrIdx[rt]) = pk_; } }

#define BR_COMPUTE(fb) { \
  _Pragma("unroll") for (int sgl = 0; sgl < 4; ++sgl) { \
    bf16x8 af_ = *(const bf16x8*)(Asg + wbase + sgl * 512 + rdOff); \
    _Pragma("unroll") for (int cb = 0; cb < 2; ++cb) { \
      bf16x8 bf_ = *(const bf16x8*)(Bs + (fb) + (sgl * 2 + cb) * 512 + l * 8); \
      acc[cb] = __builtin_amdgcn_mfma_f32_16x16x32_bf16(af_, bf_, acc[cb], 0, 0, 0); } } }

#define BR_STAGEB(half) { \
  const uint4* s_ = (const uint4*)(Wb + (half) * 12288); uint4* d_ = (uint4*)Bs; \
  _Pragma("unroll") for (int i = 0; i < 6; ++i) d_[i * 256 + t] = s_[i * 256 + t]; }

__global__ __launch_bounds__(256) void k_branch(
    const float* __restrict__ des, const float* __restrict__ twt,
    const float* __restrict__ prex, const float* __restrict__ xx,
    const u16* __restrict__ Wf,
    const float* __restrict__ bd, const float* __restrict__ btx,
    const float* __restrict__ btw, const float* __restrict__ btr,
    u16* __restrict__ h)
{
    __shared__ u16 Bs[12288];    // 24 KB: one K-half of W, frag-linear
    __shared__ u16 Asg[8192];    // 16 KB: per-wave 4-frag staging (2048 u16/wave)
    const int br = blockIdx.y;
    const float* A; const float* bias; int colBase;
    switch (br) {
      case 0:  A = des;  bias = bd;  colBase = 64;  break;
      case 1:  A = twt;  bias = btx; colBase = 96;  break;
      case 2:  A = prex; bias = btw; colBase = 128; break;
      default: A = xx;   bias = btr; colBase = 160; break;
    }
    const u16* Wb = Wf + br * 24576;

    const int t = threadIdx.x, w = t >> 6, l = t & 63;
    const int hi = l >> 4, lr = l & 15;
    const int rowBase = blockIdx.x * 64;
    const int wbase = w * 2048;
    const int rdOff = (l ^ hi) * 8;

    // A staging: run rt covers row16 = rt*4+hi, k8 = lr (8-float unit in chunk)
    const float* abase[4];
    int wrIdx[4];
    #pragma unroll
    for (int rt = 0; rt < 4; ++rt) {
        int r = rowBase + w * 16 + rt * 4 + hi;
        if (r >= NN) r = NN - 1;
        abase[rt] = A + (size_t)r * LMD + lr * 8;
        int slot = ((l & 3) << 4) | (rt * 4 + hi);
        wrIdx[rt] = wbase + (lr >> 2) * 512 + (slot ^ (l & 3)) * 8;
    }

    f32x4 acc[2] = {};
    float4 a0[4], a1[4], b0[4], b1[4];

    BR_LOAD(a0, a1, 0);
    BR_STAGEB(0);
    __syncthreads();
    BR_LOAD(b0, b1, 1);
    BR_WRITE(a0, a1);  BR_COMPUTE(0);
    BR_LOAD(a0, a1, 2);
    BR_WRITE(b0, b1);  BR_COMPUTE(4096);
    BR_LOAD(b0, b1, 3);
    BR_WRITE(a0, a1);  BR_COMPUTE(8192);
    __syncthreads();
    BR_STAGEB(1);
    __syncthreads();
    BR_LOAD(a0, a1, 4);
    BR_WRITE(b0, b1);  BR_COMPUTE(0);
    BR_LOAD(b0, b1, 5);
    BR_WRITE(a0, a1);  BR_COMPUTE(4096);
    BR_WRITE(b0, b1);  BR_COMPUTE(8192);

    // C/D: col = lr, row = hi*4 + rg
    #pragma unroll
    for (int cb = 0; cb < 2; ++cb) {
        int cl = cb * 16 + lr;
        float bv = bias[cl];
        #pragma unroll
        for (int rg = 0; rg < 4; ++rg) {
            int r = rowBase + w * 16 + hi * 4 + rg;
            if (r < NN)
                h[(size_t)r * HD + colBase + cl] = f2bf(lrelu(acc[cb][rg] + bv));
        }
    }
}

// ================= hidden GEMM: bf16 [N,192] @ W^T -> bf16 [N,192] =================
// 512 thr (8 waves), 128 rows/block; whole W (72 KB) in LDS; A frags pinned up-front.
template<bool BIAS, bool LRELU>
__global__ __launch_bounds__(512) void k_hgemm(
    const u16* __restrict__ A, const u16* __restrict__ Wf,
    const float* __restrict__ bias, u16* __restrict__ out)
{
    __shared__ u16 Bs[36864];
    const int t = threadIdx.x, w = t >> 6, l = t & 63;
    const int hi = l >> 4, lr = l & 15;
    const int rowBase = blockIdx.x * 128;
    {
        const uint4* s_ = (const uint4*)Wf; uint4* d_ = (uint4*)Bs;
        #pragma unroll
        for (int i = 0; i < 9; ++i) d_[i * 512 + t] = s_[i * 512 + t];
    }
    int r0 = rowBase + w * 16 + lr;
    int rowc = r0 < NN ? r0 : NN - 1;
    const u16* ap = A + (size_t)rowc * HD;
    float4 araw[6];
    #pragma unroll
    for (int sg = 0; sg < 6; ++sg) {
        araw[sg] = *(const float4*)(ap + sg * 32 + hi * 8);
        asm volatile("" :: "v"(araw[sg].x), "v"(araw[sg].y), "v"(araw[sg].z), "v"(araw[sg].w));
    }
    __syncthreads();

    f32x4 acc[12] = {};
    #pragma unroll
    for (int sg = 0; sg < 6; ++sg) {
        bf16x8 af = as_bf8(araw[sg]);
        #pragma unroll
        for (int cb = 0; cb < 12; ++cb) {
            bf16x8 bf = *(const bf16x8*)(Bs + (sg * 12 + cb) * 512 + l * 8);
            acc[cb] = __builtin_amdgcn_mfma_f32_16x16x32_bf16(af, bf, acc[cb], 0, 0, 0);
        }
    }

    #pragma unroll
    for (int cb = 0; cb < 12; ++cb) {
        int cl = cb * 16 + lr;
        float bv = BIAS ? bias[cl] : 0.f;
        #pragma unroll
        for (int rg = 0; rg < 4; ++rg) {
            int r = rowBase + w * 16 + hi * 4 + rg;
            if (r < NN) {
                float v = acc[cb][rg] + bv;
                if (LRELU) v = lrelu(v);
                out[(size_t)r * HD + cl] = f2bf(v);
            }
        }
    }
}

// ================= final: em = lrelu(hC @ Wo1^T + b1) fp32 + out = em @ Wo2^T + b2 =================
__global__ __launch_bounds__(512) void k_final(
    const u16* __restrict__ A, const u16* __restrict__ Wf,
    const float* __restrict__ b1, const float* __restrict__ W2,
    const float* __restrict__ b2, float* __restrict__ em, float* __restrict__ out)
{
    __shared__ u16 Bs[18432];
    const int t = threadIdx.x, w = t >> 6, l = t & 63;
    const int hi = l >> 4, lr = l & 15;
    const int rowBase = blockIdx.x * 128;
    {
        const uint4* s_ = (const uint4*)Wf; uint4* d_ = (uint4*)Bs;
        #pragma unroll
        for (int i = 0; i < 5; ++i) { int idx = i * 512 + t; if (idx < 2304) d_[idx] = s_[idx]; }
    }
    int r0 = rowBase + w * 16 + lr;
    int rowc = r0 < NN ? r0 : NN - 1;
    const u16* ap = A + (size_t)rowc * HD;
    float4 araw[6];
    #pragma unroll
    for (int sg = 0; sg < 6; ++sg) {
        araw[sg] = *(const float4*)(ap + sg * 32 + hi * 8);
        asm volatile("" :: "v"(araw[sg].x), "v"(araw[sg].y), "v"(araw[sg].z), "v"(araw[sg].w));
    }
    __syncthreads();

    f32x4 acc[6] = {};
    #pragma unroll
    for (int sg = 0; sg < 6; ++sg) {
        bf16x8 af = as_bf8(araw[sg]);
        #pragma unroll
        for (int cb = 0; cb < 6; ++cb) {
            bf16x8 bf = *(const bf16x8*)(Bs + (sg * 6 + cb) * 512 + l * 8);
            acc[cb] = __builtin_amdgcn_mfma_f32_16x16x32_bf16(af, bf, acc[cb], 0, 0, 0);
        }
    }

    float w2v[2][6], bv[6];
    #pragma unroll
    for (int cb = 0; cb < 6; ++cb) {
        bv[cb] = b1[cb * 16 + lr];
        w2v[0][cb] = W2[cb * 16 + lr];
        w2v[1][cb] = W2[96 + cb * 16 + lr];
    }

    #pragma unroll
    for (int rg = 0; rg < 4; ++rg) {
        int r = rowBase + w * 16 + hi * 4 + rg;
        float o0 = 0.f, o1 = 0.f;
        #pragma unroll
        for (int cb = 0; cb < 6; ++cb) {
            float v = lrelu(acc[cb][rg] + bv[cb]);
            if (r < NN) em[(size_t)r * 96 + cb * 16 + lr] = v;
            o0 += v * w2v[0][cb];
            o1 += v * w2v[1][cb];
        }
        #pragma unroll
        for (int d = 1; d < 16; d <<= 1) {
            o0 += __shfl_xor(o0, d);
            o1 += __shfl_xor(o1, d);
        }
        if (lr == 0 && r < NN) {
            out[r * 2 + 0] = o0 + b2[0];
            out[r * 2 + 1] = o1 + b2[1];
        }
    }
}

// ================= small branches: cols 0..63 =================
__global__ __launch_bounds__(256) void k_small_branch(
    const float* __restrict__ nprop, const float* __restrict__ ncat,
    const float* __restrict__ Wp, const float* __restrict__ bp,
    const float* __restrict__ Wc, const float* __restrict__ bc,
    u16* __restrict__ h)
{
    int idx = blockIdx.x * 256 + threadIdx.x;
    if (idx >= NN * 64) return;
    int row = idx >> 6, c = idx & 63;
    float acc;
    if (c < 32) {
        acc = bp[c];
        #pragma unroll
        for (int k = 0; k < 5; ++k) acc += nprop[row * 5 + k] * Wp[c * 5 + k];
    } else {
        int cc = c - 32;
        acc = bc[cc] + ncat[row] * Wc[cc];
    }
    h[(size_t)row * HD + c] = f2bf(lrelu(acc));
}

// ================= graph structure =================
__global__ void k_count(const int* __restrict__ ei, int* __restrict__ deg)
{
    int e = blockIdx.x * 256 + threadIdx.x;
    if (e < EE) atomicAdd(&deg[ei[EE + e]], 1);
}

__global__ void k_deginv(const int* __restrict__ deg, float* __restrict__ dinv, float* __restrict__ invdeg)
{
    int v = blockIdx.x * 256 + threadIdx.x;
    if (v < NN) {
        float d = (float)(deg[v] + 1);
        dinv[v] = rsqrtf(d);
        invdeg[v] = 1.0f / d;
    }
}

__global__ __launch_bounds__(1024) void k_scan1(const int* __restrict__ deg, int* __restrict__ rp, int* __restrict__ part)
{
    __shared__ int sh[1024];
    int tid = threadIdx.x, i = blockIdx.x * 1024 + tid;
    int x = (i < NN) ? deg[i] : 0;
    sh[tid] = x;
    __syncthreads();
    for (int off = 1; off < 1024; off <<= 1) {
        int y = (tid >= off) ? sh[tid - off] : 0;
        __syncthreads();
        sh[tid] += y;
        __syncthreads();
    }
    if (i < NN) rp[i] = sh[tid] - x;
    if (tid == 1023) part[blockIdx.x] = sh[tid];
}

__global__ void k_scan2(int* part, int nb, int* rp)
{
    if (threadIdx.x == 0 && blockIdx.x == 0) {
        int run = 0;
        for (int b = 0; b < nb; ++b) { int t = part[b]; part[b] = run; run += t; }
        rp[NN] = run;
    }
}

__global__ void k_scan3(int* rp, const int* __restrict__ part)
{
    int i = blockIdx.x * 256 + threadIdx.x;
    if (i < NN) rp[i] += part[i >> 10];
}

__global__ void k_fill(const int* __restrict__ ei, const float* __restrict__ dinv,
                       int* __restrict__ cursor, int* __restrict__ cs, float* __restrict__ nrm)
{
    int e = blockIdx.x * 256 + threadIdx.x;
    if (e >= EE) return;
    int s = ei[e], d = ei[EE + e];
    int pos = atomicAdd(&cursor[d], 1);
    cs[pos] = s;
    nrm[pos] = dinv[s] * dinv[d];
}

// ================= GCN aggregation =================
__global__ __launch_bounds__(240) void k_agg(const u16* __restrict__ hW,
    const int* __restrict__ rp, const int* __restrict__ cs, const float* __restrict__ nrm,
    const float* __restrict__ invdeg, const float* __restrict__ bias, u16* __restrict__ out)
{
    int v = blockIdx.x * 5 + threadIdx.y;
    int f0 = threadIdx.x * 4;
    int s0 = rp[v], s1 = rp[v + 1];
    float4 bv = *reinterpret_cast<const float4*>(bias + f0);
    ushort4 hv = *reinterpret_cast<const ushort4*>(hW + (size_t)v * HD + f0);
    float idg = invdeg[v];
    float a0 = bf2f(hv.x) * idg + bv.x;
    float a1 = bf2f(hv.y) * idg + bv.y;
    float a2 = bf2f(hv.z) * idg + bv.z;
    float a3 = bf2f(hv.w) * idg + bv.w;
    int i = s0;
    for (; i + 4 <= s1; i += 4) {
        int c0 = cs[i], c1 = cs[i+1], c2 = cs[i+2], c3 = cs[i+3];
        float n0 = nrm[i], n1 = nrm[i+1], n2 = nrm[i+2], n3 = nrm[i+3];
        ushort4 g0 = *reinterpret_cast<const ushort4*>(hW + (size_t)c0 * HD + f0);
        ushort4 g1 = *reinterpret_cast<const ushort4*>(hW + (size_t)c1 * HD + f0);
        ushort4 g2 = *reinterpret_cast<const ushort4*>(hW + (size_t)c2 * HD + f0);
        ushort4 g3 = *reinterpret_cast<const ushort4*>(hW + (size_t)c3 * HD + f0);
        a0 += bf2f(g0.x) * n0; a1 += bf2f(g0.y) * n0; a2 += bf2f(g0.z) * n0; a3 += bf2f(g0.w) * n0;
        a0 += bf2f(g1.x) * n1; a1 += bf2f(g1.y) * n1; a2 += bf2f(g1.z) * n1; a3 += bf2f(g1.w) * n1;
        a0 += bf2f(g2.x) * n2; a1 += bf2f(g2.y) * n2; a2 += bf2f(g2.z) * n2; a3 += bf2f(g2.w) * n2;
        a0 += bf2f(g3.x) * n3; a1 += bf2f(g3.y) * n3; a2 += bf2f(g3.z) * n3; a3 += bf2f(g3.w) * n3;
    }
    for (; i < s1; ++i) {
        int c = cs[i]; float n = nrm[i];
        ushort4 g = *reinterpret_cast<const ushort4*>(hW + (size_t)c * HD + f0);
        a0 += bf2f(g.x) * n; a1 += bf2f(g.y) * n; a2 += bf2f(g.z) * n; a3 += bf2f(g.w) * n;
    }
    ushort4 o;
    o.x = f2bf(a0); o.y = f2bf(a1); o.z = f2bf(a2); o.w = f2bf(a3);
    *reinterpret_cast<ushort4*>(out + (size_t)v * HD + f0) = o;
}

extern "C" void kernel_launch(void* const* d_in, const int* in_sizes, int n_in,
                              void* d_out, int out_size, void* d_ws, size_t ws_size,
                              hipStream_t stream)
{
    const float* pre_x = (const float*)d_in[0];
    const float* x     = (const float*)d_in[1];
    const int*   ei    = (const int*)d_in[2];
    const float* nprop = (const float*)d_in[4];
    const float* ncat  = (const float*)d_in[5];
    const float* des   = (const float*)d_in[6];
    const float* twt   = (const float*)d_in[7];
    const float* W_des  = (const float*)d_in[8],  *b_des  = (const float*)d_in[9];
    const float* W_tw   = (const float*)d_in[10], *b_tw   = (const float*)d_in[11];
    const float* W_tr   = (const float*)d_in[12], *b_tr   = (const float*)d_in[13];
    const float* W_prop = (const float*)d_in[14], *b_prop = (const float*)d_in[15];
    const float* W_cat  = (const float*)d_in[16], *b_cat  = (const float*)d_in[17];
    const float* W_text = (const float*)d_in[18], *b_text = (const float*)d_in[19];
    const float* W_in   = (const float*)d_in[20], *b_in   = (const float*)d_in[21];
    const float* W_c1   = (const float*)d_in[22], *b_c1   = (const float*)d_in[23];
    const float* W_c2   = (const float*)d_in[24], *b_c2   = (const float*)d_in[25];
    const float* W_o1   = (const float*)d_in[26], *b_o1   = (const float*)d_in[27];
    const float* W_o2   = (const float*)d_in[28], *b_o2   = (const float*)d_in[29];

    char* base = (char*)d_ws;
    size_t off = 0;
    auto alloc = [&](size_t bytes) -> char* {
        char* p = base + off;
        off = (off + bytes + 255) & ~(size_t)255;
        return p;
    };
    u16*   hA     = (u16*)alloc((size_t)NN * HD * 2);
    u16*   hB     = (u16*)alloc((size_t)NN * HD * 2);
    u16*   hC     = (u16*)alloc((size_t)NN * HD * 2);
    u16*   Wprep  = (u16*)alloc((size_t)227328 * 2);
    float* dinv   = (float*)alloc((size_t)NN * 4);
    float* invdeg = (float*)alloc((size_t)NN * 4);
    int*   deg    = (int*)alloc((size_t)NN * 4);
    int*   rp     = (int*)alloc((size_t)(NN + 1) * 4);
    int*   cursor = (int*)alloc((size_t)NN * 4);
    int*   part   = (int*)alloc(64 * 4);
    int*   cs     = (int*)alloc((size_t)EE * 4);
    float* nrm    = (float*)alloc((size_t)EE * 4);
    (void)ws_size; (void)in_sizes; (void)n_in; (void)out_size;

    float* outp = (float*)d_out;            // [N,2]
    float* em   = outp + (size_t)NN * 2;    // [N,96] fp32

    const int rb     = (NN + 255) / 256;    // 196
    const int rb64   = (NN + 63) / 64;      // 782
    const int rb128  = (NN + 127) / 128;    // 391
    const int eb     = (EE + 255) / 256;    // 3125
    const int nb1024 = (NN + 1023) / 1024;  // 49

    // ---- weight prep + graph structure ----
    hipMemsetAsync(deg, 0, (size_t)NN * 4, stream);
    hipLaunchKernelGGL(k_prep, dim3(144, 8), dim3(256), 0, stream,
        W_des, W_text, W_tw, W_tr, W_in, W_c1, W_c2, W_o1, Wprep);
    hipLaunchKernelGGL(k_count,  dim3(eb), dim3(256), 0, stream, ei, deg);
    hipLaunchKernelGGL(k_deginv, dim3(rb), dim3(256), 0, stream, deg, dinv, invdeg);
    hipLaunchKernelGGL(k_scan1,  dim3(nb1024), dim3(1024), 0, stream, deg, rp, part);
    hipLaunchKernelGGL(k_scan2,  dim3(1), dim3(1), 0, stream, part, nb1024, rp);
    hipLaunchKernelGGL(k_scan3,  dim3(rb), dim3(256), 0, stream, rp, part);
    hipMemcpyAsync(cursor, rp, (size_t)NN * 4, hipMemcpyDeviceToDevice, stream);
    hipLaunchKernelGGL(k_fill,   dim3(eb), dim3(256), 0, stream, ei, dinv, cursor, cs, nrm);

    // ---- feature path ----
    hipLaunchKernelGGL(k_branch, dim3(rb64, 4), dim3(256), 0, stream,
        des, twt, pre_x, x, Wprep, b_des, b_text, b_tw, b_tr, hA);
    hipLaunchKernelGGL(k_small_branch, dim3((NN * 64 + 255) / 256), dim3(256), 0, stream,
        nprop, ncat, W_prop, b_prop, W_cat, b_cat, hA);

    hipLaunchKernelGGL((k_hgemm<true, true>),   dim3(rb128), dim3(512), 0, stream,
        hA, Wprep + 98304, b_in, hB);
    hipLaunchKernelGGL((k_hgemm<false, false>), dim3(rb128), dim3(512), 0, stream,
        hB, Wprep + 98304 + 36864, nullptr, hC);
    hipLaunchKernelGGL(k_agg, dim3(NN / 5), dim3(48, 5), 0, stream, hC, rp, cs, nrm, invdeg, b_c1, hA);
    hipLaunchKernelGGL((k_hgemm<false, false>), dim3(rb128), dim3(512), 0, stream,
        hA, Wprep + 98304 + 2 * 36864, nullptr, hB);
    hipLaunchKernelGGL(k_agg, dim3(NN / 5), dim3(48, 5), 0, stream, hB, rp, cs, nrm, invdeg, b_c2, hC);

    hipLaunchKernelGGL(k_final, dim3(rb128), dim3(512), 0, stream,
        hC, Wprep + 208896, b_o1, W_o2, b_o2, em, outp);
}

// Round 6
// 405.269 us; speedup vs baseline: 3.7793x; 1.0121x over previous
//
#include <hip/hip_runtime.h>

#define NN 50000
#define EE 800000
#define LMD 768
#define HD 192
#define SLOPE 0.01f

typedef short bf16x8 __attribute__((ext_vector_type(8)));
typedef float f32x4 __attribute__((ext_vector_type(4)));
typedef unsigned short u16;

__device__ __forceinline__ float lrelu(float v){ return v > 0.f ? v : SLOPE * v; }

__device__ __forceinline__ u16 f2bf(float f){
    unsigned u = __float_as_uint(f);
    u += 0x7FFF + ((u >> 16) & 1u);
    return (u16)(u >> 16);
}
__device__ __forceinline__ float bf2f(u16 v){
    return __uint_as_float(((unsigned)v) << 16);
}
__device__ __forceinline__ bf16x8 as_bf8(float4 v){
    union { float4 f; bf16x8 b; } u; u.f = v; return u.b;
}

#define GLOAD16(gp, lp) __builtin_amdgcn_global_load_lds( \
    (const __attribute__((address_space(1))) void*)(gp), \
    (__attribute__((address_space(3))) void*)(lp), 16, 0, 0)

// ================= weight prep: fp32 -> bf16 frag-linear =================
// frag (16x16x32): lane = hi*16 + lr; B elem col=lr, k = sg*32 + hi*8 + j.
// storage: frag_id*512 + lane*8 + j.
__global__ __launch_bounds__(256) void k_prep(
    const float* __restrict__ W0, const float* __restrict__ W1,
    const float* __restrict__ W2, const float* __restrict__ W3,
    const float* __restrict__ Win, const float* __restrict__ Wc1,
    const float* __restrict__ Wc2, const float* __restrict__ Wo1,
    u16* __restrict__ out)
{
    int m = blockIdx.y;
    int idx = blockIdx.x * 256 + threadIdx.x;
    const float* src; int nelem; int K;
    switch (m) {
      case 0: src = W0;  nelem = 32*768;  K = 768; break;
      case 1: src = W1;  nelem = 32*768;  K = 768; break;
      case 2: src = W2;  nelem = 32*768;  K = 768; break;
      case 3: src = W3;  nelem = 32*768;  K = 768; break;
      case 4: src = Win; nelem = 192*192; K = 192; break;
      case 5: src = Wc1; nelem = 192*192; K = 192; break;
      case 6: src = Wc2; nelem = 192*192; K = 192; break;
      default: src = Wo1; nelem = 96*192; K = 192; break;
    }
    if (idx >= nelem) return;
    u16 v = f2bf(src[idx]);
    int c = idx / K, k = idx - c * K;
    int cb = c >> 4, lr = c & 15;
    int sg = k >> 5, kk = k & 31, hi = kk >> 3, j = kk & 7;
    int lane = hi * 16 + lr;
    size_t dst;
    if (m < 4)      dst = (size_t)m * 24576 + (sg * 2 + cb) * 512 + lane * 8 + j;
    else if (m < 7) dst = 98304 + (size_t)(m - 4) * 36864 + (sg * 12 + cb) * 512 + lane * 8 + j;
    else            dst = 208896 + (size_t)(sg * 6 + cb) * 512 + lane * 8 + j;
    out[dst] = v;
}

// ================= big branches: [N,768] fp32 -> bf16 h cols =================
// 256 thr (4 waves), BM=64 rows. A: global_load_lds fp32, BK=32, 3-buffer
// rotation, wave-private rows, counted vmcnt, ZERO K-loop barriers.
// W: 48 KB frag-linear staged once. LDS 72 KB -> 2 blocks/CU.
__global__ __launch_bounds__(256) void k_branch(
    const float* __restrict__ des, const float* __restrict__ twt,
    const float* __restrict__ prex, const float* __restrict__ xx,
    const u16* __restrict__ Wf,
    const float* __restrict__ bd, const float* __restrict__ btx,
    const float* __restrict__ btw, const float* __restrict__ btr,
    u16* __restrict__ h)
{
    __shared__ u16 Ws_[24576];          // 48 KB: all 48 B-frags of this branch
    __shared__ float Ab[3][64][32];     // 3 x 8 KB A chunk buffers (fp32, swizzled)

    const int br = blockIdx.y;
    const float* A; const float* bias; int colBase;
    switch (br) {
      case 0:  A = des;  bias = bd;  colBase = 64;  break;
      case 1:  A = twt;  bias = btx; colBase = 96;  break;
      case 2:  A = prex; bias = btw; colBase = 128; break;
      default: A = xx;   bias = btr; colBase = 160; break;
    }

    const int t = threadIdx.x, w = t >> 6, l = t & 63;
    const int hi = l >> 4, lr = l & 15;
    const int rowBase = blockIdx.x * 64;

    // ---- stage W (once) ----
    {
        const uint4* s_ = (const uint4*)(Wf + br * 24576);
        uint4* d_ = (uint4*)Ws_;
        #pragma unroll
        for (int i = 0; i < 12; ++i) d_[i * 256 + t] = s_[i * 256 + t];
    }
    __syncthreads();

    // ---- A staging: wave-private (wave w stages exactly rows w*16..w*16+15) ----
    // per instr i (0,1): rows w*16+i*8+(l>>3); 16-B slot s16=l&7; 32-B slot g=s16>>1
    // source-swizzled: g' = g ^ (row&3); LDS dest linear (base + lane*16)
    const int rl_ = w * 16 + (l >> 3);      // +i*8
    const int s16 = l & 7, g_ = s16 >> 1, hf = s16 & 1;

#define STAGE(cc, bufi) { \
    _Pragma("unroll") for (int i_ = 0; i_ < 2; ++i_) { \
        int rl = rl_ + i_ * 8; \
        int rg = rowBase + rl; if (rg >= NN) rg = NN - 1; \
        const float* gp = A + (size_t)rg * LMD + (cc) * 32 + ((g_ ^ (rl & 3)) * 8 + hf * 4); \
        GLOAD16(gp, &Ab[bufi][w * 16 + i_ * 8][0]); } }

    STAGE(0, 0);
    STAGE(1, 1);

    f32x4 acc[2] = {};

    #pragma unroll
    for (int c = 0; c < 24; ++c) {
        if (c + 2 < 24) {
            const int bufi = (c + 2) % 3;
            STAGE(c + 2, bufi);
        }
        if (c < 22)      { asm volatile("s_waitcnt vmcnt(4)" ::: "memory"); }
        else if (c == 22){ asm volatile("s_waitcnt vmcnt(2)" ::: "memory"); }
        else             { asm volatile("s_waitcnt vmcnt(0)" ::: "memory"); }
        __builtin_amdgcn_sched_barrier(0);

        // frag read: row = w*16+lr, k = hi*8..+7 -> slot (hi ^ (lr&3))
        const float* ab = &Ab[c % 3][w * 16 + lr][(hi ^ (lr & 3)) * 8];
        float4 lo = *(const float4*)ab;
        float4 hp = *(const float4*)(ab + 4);
        bf16x8 af;
        af[0] = (short)f2bf(lo.x); af[1] = (short)f2bf(lo.y);
        af[2] = (short)f2bf(lo.z); af[3] = (short)f2bf(lo.w);
        af[4] = (short)f2bf(hp.x); af[5] = (short)f2bf(hp.y);
        af[6] = (short)f2bf(hp.z); af[7] = (short)f2bf(hp.w);
        #pragma unroll
        for (int cb = 0; cb < 2; ++cb) {
            bf16x8 bf = *(const bf16x8*)(Ws_ + (c * 2 + cb) * 512 + l * 8);
            acc[cb] = __builtin_amdgcn_mfma_f32_16x16x32_bf16(af, bf, acc[cb], 0, 0, 0);
        }
    }
#undef STAGE

    // C/D: col = lr, row = hi*4 + rg
    #pragma unroll
    for (int cb = 0; cb < 2; ++cb) {
        int cl = cb * 16 + lr;
        float bv = bias[cl];
        #pragma unroll
        for (int rg = 0; rg < 4; ++rg) {
            int r = rowBase + w * 16 + hi * 4 + rg;
            if (r < NN)
                h[(size_t)r * HD + colBase + cl] = f2bf(lrelu(acc[cb][rg] + bv));
        }
    }
}

// ================= hidden GEMM: bf16 [N,192] @ W^T -> bf16 [N,192] =================
template<bool BIAS, bool LRELU>
__global__ __launch_bounds__(512) void k_hgemm(
    const u16* __restrict__ A, const u16* __restrict__ Wf,
    const float* __restrict__ bias, u16* __restrict__ out)
{
    __shared__ u16 Bs[36864];
    const int t = threadIdx.x, w = t >> 6, l = t & 63;
    const int hi = l >> 4, lr = l & 15;
    const int rowBase = blockIdx.x * 128;
    {
        const uint4* s_ = (const uint4*)Wf; uint4* d_ = (uint4*)Bs;
        #pragma unroll
        for (int i = 0; i < 9; ++i) d_[i * 512 + t] = s_[i * 512 + t];
    }
    int r0 = rowBase + w * 16 + lr;
    int rowc = r0 < NN ? r0 : NN - 1;
    const u16* ap = A + (size_t)rowc * HD;
    float4 araw[6];
    #pragma unroll
    for (int sg = 0; sg < 6; ++sg) {
        araw[sg] = *(const float4*)(ap + sg * 32 + hi * 8);
        asm volatile("" :: "v"(araw[sg].x), "v"(araw[sg].y), "v"(araw[sg].z), "v"(araw[sg].w));
    }
    __syncthreads();

    f32x4 acc[12] = {};
    #pragma unroll
    for (int sg = 0; sg < 6; ++sg) {
        bf16x8 af = as_bf8(araw[sg]);
        #pragma unroll
        for (int cb = 0; cb < 12; ++cb) {
            bf16x8 bf = *(const bf16x8*)(Bs + (sg * 12 + cb) * 512 + l * 8);
            acc[cb] = __builtin_amdgcn_mfma_f32_16x16x32_bf16(af, bf, acc[cb], 0, 0, 0);
        }
    }

    #pragma unroll
    for (int cb = 0; cb < 12; ++cb) {
        int cl = cb * 16 + lr;
        float bv = BIAS ? bias[cl] : 0.f;
        #pragma unroll
        for (int rg = 0; rg < 4; ++rg) {
            int r = rowBase + w * 16 + hi * 4 + rg;
            if (r < NN) {
                float v = acc[cb][rg] + bv;
                if (LRELU) v = lrelu(v);
                out[(size_t)r * HD + cl] = f2bf(v);
            }
        }
    }
}

// ================= final: em = lrelu(hC @ Wo1^T + b1) fp32 + out = em @ Wo2^T + b2 =================
__global__ __launch_bounds__(512) void k_final(
    const u16* __restrict__ A, const u16* __restrict__ Wf,
    const float* __restrict__ b1, const float* __restrict__ W2,
    const float* __restrict__ b2, float* __restrict__ em, float* __restrict__ out)
{
    __shared__ u16 Bs[18432];
    const int t = threadIdx.x, w = t >> 6, l = t & 63;
    const int hi = l >> 4, lr = l & 15;
    const int rowBase = blockIdx.x * 128;
    {
        const uint4* s_ = (const uint4*)Wf; uint4* d_ = (uint4*)Bs;
        #pragma unroll
        for (int i = 0; i < 5; ++i) { int idx = i * 512 + t; if (idx < 2304) d_[idx] = s_[idx]; }
    }
    int r0 = rowBase + w * 16 + lr;
    int rowc = r0 < NN ? r0 : NN - 1;
    const u16* ap = A + (size_t)rowc * HD;
    float4 araw[6];
    #pragma unroll
    for (int sg = 0; sg < 6; ++sg) {
        araw[sg] = *(const float4*)(ap + sg * 32 + hi * 8);
        asm volatile("" :: "v"(araw[sg].x), "v"(araw[sg].y), "v"(araw[sg].z), "v"(araw[sg].w));
    }
    __syncthreads();

    f32x4 acc[6] = {};
    #pragma unroll
    for (int sg = 0; sg < 6; ++sg) {
        bf16x8 af = as_bf8(araw[sg]);
        #pragma unroll
        for (int cb = 0; cb < 6; ++cb) {
            bf16x8 bf = *(const bf16x8*)(Bs + (sg * 6 + cb) * 512 + l * 8);
            acc[cb] = __builtin_amdgcn_mfma_f32_16x16x32_bf16(af, bf, acc[cb], 0, 0, 0);
        }
    }

    float w2v[2][6], bv[6];
    #pragma unroll
    for (int cb = 0; cb < 6; ++cb) {
        bv[cb] = b1[cb * 16 + lr];
        w2v[0][cb] = W2[cb * 16 + lr];
        w2v[1][cb] = W2[96 + cb * 16 + lr];
    }

    #pragma unroll
    for (int rg = 0; rg < 4; ++rg) {
        int r = rowBase + w * 16 + hi * 4 + rg;
        float o0 = 0.f, o1 = 0.f;
        #pragma unroll
        for (int cb = 0; cb < 6; ++cb) {
            float v = lrelu(acc[cb][rg] + bv[cb]);
            if (r < NN) em[(size_t)r * 96 + cb * 16 + lr] = v;
            o0 += v * w2v[0][cb];
            o1 += v * w2v[1][cb];
        }
        #pragma unroll
        for (int d = 1; d < 16; d <<= 1) {
            o0 += __shfl_xor(o0, d);
            o1 += __shfl_xor(o1, d);
        }
        if (lr == 0 && r < NN) {
            out[r * 2 + 0] = o0 + b2[0];
            out[r * 2 + 1] = o1 + b2[1];
        }
    }
}

// ================= small branches: cols 0..63 =================
__global__ __launch_bounds__(256) void k_small_branch(
    const float* __restrict__ nprop, const float* __restrict__ ncat,
    const float* __restrict__ Wp, const float* __restrict__ bp,
    const float* __restrict__ Wc, const float* __restrict__ bc,
    u16* __restrict__ h)
{
    int idx = blockIdx.x * 256 + threadIdx.x;
    if (idx >= NN * 64) return;
    int row = idx >> 6, c = idx & 63;
    float acc;
    if (c < 32) {
        acc = bp[c];
        #pragma unroll
        for (int k = 0; k < 5; ++k) acc += nprop[row * 5 + k] * Wp[c * 5 + k];
    } else {
        int cc = c - 32;
        acc = bc[cc] + ncat[row] * Wc[cc];
    }
    h[(size_t)row * HD + c] = f2bf(lrelu(acc));
}

// ================= graph structure =================
__global__ void k_count(const int* __restrict__ ei, int* __restrict__ deg)
{
    int e = blockIdx.x * 256 + threadIdx.x;
    if (e < EE) atomicAdd(&deg[ei[EE + e]], 1);
}

__global__ void k_deginv(const int* __restrict__ deg, float* __restrict__ dinv, float* __restrict__ invdeg)
{
    int v = blockIdx.x * 256 + threadIdx.x;
    if (v < NN) {
        float d = (float)(deg[v] + 1);
        dinv[v] = rsqrtf(d);
        invdeg[v] = 1.0f / d;
    }
}

__global__ __launch_bounds__(1024) void k_scan1(const int* __restrict__ deg, int* __restrict__ rp, int* __restrict__ part)
{
    __shared__ int sh[1024];
    int tid = threadIdx.x, i = blockIdx.x * 1024 + tid;
    int x = (i < NN) ? deg[i] : 0;
    sh[tid] = x;
    __syncthreads();
    for (int off = 1; off < 1024; off <<= 1) {
        int y = (tid >= off) ? sh[tid - off] : 0;
        __syncthreads();
        sh[tid] += y;
        __syncthreads();
    }
    if (i < NN) rp[i] = sh[tid] - x;
    if (tid == 1023) part[blockIdx.x] = sh[tid];
}

__global__ void k_scan2(int* part, int nb, int* rp)
{
    if (threadIdx.x == 0 && blockIdx.x == 0) {
        int run = 0;
        for (int b = 0; b < nb; ++b) { int t = part[b]; part[b] = run; run += t; }
        rp[NN] = run;
    }
}

__global__ void k_scan3(int* rp, const int* __restrict__ part)
{
    int i = blockIdx.x * 256 + threadIdx.x;
    if (i < NN) rp[i] += part[i >> 10];
}

__global__ void k_fill(const int* __restrict__ ei, const float* __restrict__ dinv,
                       int* __restrict__ cursor, int* __restrict__ cs, float* __restrict__ nrm)
{
    int e = blockIdx.x * 256 + threadIdx.x;
    if (e >= EE) return;
    int s = ei[e], d = ei[EE + e];
    int pos = atomicAdd(&cursor[d], 1);
    cs[pos] = s;
    nrm[pos] = dinv[s] * dinv[d];
}

// ================= GCN aggregation =================
__global__ __launch_bounds__(240) void k_agg(const u16* __restrict__ hW,
    const int* __restrict__ rp, const int* __restrict__ cs, const float* __restrict__ nrm,
    const float* __restrict__ invdeg, const float* __restrict__ bias, u16* __restrict__ out)
{
    int v = blockIdx.x * 5 + threadIdx.y;
    int f0 = threadIdx.x * 4;
    int s0 = rp[v], s1 = rp[v + 1];
    float4 bv = *reinterpret_cast<const float4*>(bias + f0);
    ushort4 hv = *reinterpret_cast<const ushort4*>(hW + (size_t)v * HD + f0);
    float idg = invdeg[v];
    float a0 = bf2f(hv.x) * idg + bv.x;
    float a1 = bf2f(hv.y) * idg + bv.y;
    float a2 = bf2f(hv.z) * idg + bv.z;
    float a3 = bf2f(hv.w) * idg + bv.w;
    int i = s0;
    for (; i + 4 <= s1; i += 4) {
        int c0 = cs[i], c1 = cs[i+1], c2 = cs[i+2], c3 = cs[i+3];
        float n0 = nrm[i], n1 = nrm[i+1], n2 = nrm[i+2], n3 = nrm[i+3];
        ushort4 g0 = *reinterpret_cast<const ushort4*>(hW + (size_t)c0 * HD + f0);
        ushort4 g1 = *reinterpret_cast<const ushort4*>(hW + (size_t)c1 * HD + f0);
        ushort4 g2 = *reinterpret_cast<const ushort4*>(hW + (size_t)c2 * HD + f0);
        ushort4 g3 = *reinterpret_cast<const ushort4*>(hW + (size_t)c3 * HD + f0);
        a0 += bf2f(g0.x) * n0; a1 += bf2f(g0.y) * n0; a2 += bf2f(g0.z) * n0; a3 += bf2f(g0.w) * n0;
        a0 += bf2f(g1.x) * n1; a1 += bf2f(g1.y) * n1; a2 += bf2f(g1.z) * n1; a3 += bf2f(g1.w) * n1;
        a0 += bf2f(g2.x) * n2; a1 += bf2f(g2.y) * n2; a2 += bf2f(g2.z) * n2; a3 += bf2f(g2.w) * n2;
        a0 += bf2f(g3.x) * n3; a1 += bf2f(g3.y) * n3; a2 += bf2f(g3.z) * n3; a3 += bf2f(g3.w) * n3;
    }
    for (; i < s1; ++i) {
        int c = cs[i]; float n = nrm[i];
        ushort4 g = *reinterpret_cast<const ushort4*>(hW + (size_t)c * HD + f0);
        a0 += bf2f(g.x) * n; a1 += bf2f(g.y) * n; a2 += bf2f(g.z) * n; a3 += bf2f(g.w) * n;
    }
    ushort4 o;
    o.x = f2bf(a0); o.y = f2bf(a1); o.z = f2bf(a2); o.w = f2bf(a3);
    *reinterpret_cast<ushort4*>(out + (size_t)v * HD + f0) = o;
}

extern "C" void kernel_launch(void* const* d_in, const int* in_sizes, int n_in,
                              void* d_out, int out_size, void* d_ws, size_t ws_size,
                              hipStream_t stream)
{
    const float* pre_x = (const float*)d_in[0];
    const float* x     = (const float*)d_in[1];
    const int*   ei    = (const int*)d_in[2];
    const float* nprop = (const float*)d_in[4];
    const float* ncat  = (const float*)d_in[5];
    const float* des   = (const float*)d_in[6];
    const float* twt   = (const float*)d_in[7];
    const float* W_des  = (const float*)d_in[8],  *b_des  = (const float*)d_in[9];
    const float* W_tw   = (const float*)d_in[10], *b_tw   = (const float*)d_in[11];
    const float* W_tr   = (const float*)d_in[12], *b_tr   = (const float*)d_in[13];
    const float* W_prop = (const float*)d_in[14], *b_prop = (const float*)d_in[15];
    const float* W_cat  = (const float*)d_in[16], *b_cat  = (const float*)d_in[17];
    const float* W_text = (const float*)d_in[18], *b_text = (const float*)d_in[19];
    const float* W_in   = (const float*)d_in[20], *b_in   = (const float*)d_in[21];
    const float* W_c1   = (const float*)d_in[22], *b_c1   = (const float*)d_in[23];
    const float* W_c2   = (const float*)d_in[24], *b_c2   = (const float*)d_in[25];
    const float* W_o1   = (const float*)d_in[26], *b_o1   = (const float*)d_in[27];
    const float* W_o2   = (const float*)d_in[28], *b_o2   = (const float*)d_in[29];

    char* base = (char*)d_ws;
    size_t off = 0;
    auto alloc = [&](size_t bytes) -> char* {
        char* p = base + off;
        off = (off + bytes + 255) & ~(size_t)255;
        return p;
    };
    u16*   hA     = (u16*)alloc((size_t)NN * HD * 2);
    u16*   hB     = (u16*)alloc((size_t)NN * HD * 2);
    u16*   hC     = (u16*)alloc((size_t)NN * HD * 2);
    u16*   Wprep  = (u16*)alloc((size_t)227328 * 2);
    float* dinv   = (float*)alloc((size_t)NN * 4);
    float* invdeg = (float*)alloc((size_t)NN * 4);
    int*   deg    = (int*)alloc((size_t)NN * 4);
    int*   rp     = (int*)alloc((size_t)(NN + 1) * 4);
    int*   cursor = (int*)alloc((size_t)NN * 4);
    int*   part   = (int*)alloc(64 * 4);
    int*   cs     = (int*)alloc((size_t)EE * 4);
    float* nrm    = (float*)alloc((size_t)EE * 4);
    (void)ws_size; (void)in_sizes; (void)n_in; (void)out_size;

    float* outp = (float*)d_out;            // [N,2]
    float* em   = outp + (size_t)NN * 2;    // [N,96] fp32

    const int rb     = (NN + 255) / 256;    // 196
    const int rb64   = (NN + 63) / 64;      // 782
    const int rb128  = (NN + 127) / 128;    // 391
    const int eb     = (EE + 255) / 256;    // 3125
    const int nb1024 = (NN + 1023) / 1024;  // 49

    // ---- weight prep + graph structure ----
    hipMemsetAsync(deg, 0, (size_t)NN * 4, stream);
    hipLaunchKernelGGL(k_prep, dim3(144, 8), dim3(256), 0, stream,
        W_des, W_text, W_tw, W_tr, W_in, W_c1, W_c2, W_o1, Wprep);
    hipLaunchKernelGGL(k_count,  dim3(eb), dim3(256), 0, stream, ei, deg);
    hipLaunchKernelGGL(k_deginv, dim3(rb), dim3(256), 0, stream, deg, dinv, invdeg);
    hipLaunchKernelGGL(k_scan1,  dim3(nb1024), dim3(1024), 0, stream, deg, rp, part);
    hipLaunchKernelGGL(k_scan2,  dim3(1), dim3(1), 0, stream, part, nb1024, rp);
    hipLaunchKernelGGL(k_scan3,  dim3(rb), dim3(256), 0, stream, rp, part);
    hipMemcpyAsync(cursor, rp, (size_t)NN * 4, hipMemcpyDeviceToDevice, stream);
    hipLaunchKernelGGL(k_fill,   dim3(eb), dim3(256), 0, stream, ei, dinv, cursor, cs, nrm);

    // ---- feature path ----
    hipLaunchKernelGGL(k_branch, dim3(rb64, 4), dim3(256), 0, stream,
        des, twt, pre_x, x, Wprep, b_des, b_text, b_tw, b_tr, hA);
    hipLaunchKernelGGL(k_small_branch, dim3((NN * 64 + 255) / 256), dim3(256), 0, stream,
        nprop, ncat, W_prop, b_prop, W_cat, b_cat, hA);

    hipLaunchKernelGGL((k_hgemm<true, true>),   dim3(rb128), dim3(512), 0, stream,
        hA, Wprep + 98304, b_in, hB);
    hipLaunchKernelGGL((k_hgemm<false, false>), dim3(rb128), dim3(512), 0, stream,
        hB, Wprep + 98304 + 36864, nullptr, hC);
    hipLaunchKernelGGL(k_agg, dim3(NN / 5), dim3(48, 5), 0, stream, hC, rp, cs, nrm, invdeg, b_c1, hA);
    hipLaunchKernelGGL((k_hgemm<false, false>), dim3(rb128), dim3(512), 0, stream,
        hA, Wprep + 98304 + 2 * 36864, nullptr, hB);
    hipLaunchKernelGGL(k_agg, dim3(NN / 5), dim3(48, 5), 0, stream, hB, rp, cs, nrm, invdeg, b_c2, hC);

    hipLaunchKernelGGL(k_final, dim3(rb128), dim3(512), 0, stream,
        hC, Wprep + 208896, b_o1, W_o2, b_o2, em, outp);
}

// Round 7
// 399.064 us; speedup vs baseline: 3.8381x; 1.0155x over previous
//
#include <hip/hip_runtime.h>

#define NN 50000
#define EE 800000
#define LMD 768
#define HD 192
#define SLOPE 0.01f

typedef short bf16x8 __attribute__((ext_vector_type(8)));
typedef float f32x4 __attribute__((ext_vector_type(4)));
typedef unsigned short u16;

__device__ __forceinline__ float lrelu(float v){ return v > 0.f ? v : SLOPE * v; }

__device__ __forceinline__ u16 f2bf(float f){
    unsigned u = __float_as_uint(f);
    u += 0x7FFF + ((u >> 16) & 1u);
    return (u16)(u >> 16);
}
__device__ __forceinline__ float bf2f(u16 v){
    return __uint_as_float(((unsigned)v) << 16);
}
__device__ __forceinline__ bf16x8 as_bf8(float4 v){
    union { float4 f; bf16x8 b; } u; u.f = v; return u.b;
}

// ================= weight prep: fp32 -> bf16 frag-linear =================
// frag (16x16x32): lane = hi*16 + lr; B elem col=lr, k = sg*32 + hi*8 + j.
// storage: frag_id*512 + lane*8 + j.
__global__ __launch_bounds__(256) void k_prep(
    const float* __restrict__ W0, const float* __restrict__ W1,
    const float* __restrict__ W2, const float* __restrict__ W3,
    const float* __restrict__ Win, const float* __restrict__ Wc1,
    const float* __restrict__ Wc2, const float* __restrict__ Wo1,
    u16* __restrict__ out)
{
    int m = blockIdx.y;
    int idx = blockIdx.x * 256 + threadIdx.x;
    const float* src; int nelem; int K;
    switch (m) {
      case 0: src = W0;  nelem = 32*768;  K = 768; break;
      case 1: src = W1;  nelem = 32*768;  K = 768; break;
      case 2: src = W2;  nelem = 32*768;  K = 768; break;
      case 3: src = W3;  nelem = 32*768;  K = 768; break;
      case 4: src = Win; nelem = 192*192; K = 192; break;
      case 5: src = Wc1; nelem = 192*192; K = 192; break;
      case 6: src = Wc2; nelem = 192*192; K = 192; break;
      default: src = Wo1; nelem = 96*192; K = 192; break;
    }
    if (idx >= nelem) return;
    u16 v = f2bf(src[idx]);
    int c = idx / K, k = idx - c * K;
    int cb = c >> 4, lr = c & 15;
    int sg = k >> 5, kk = k & 31, hi = kk >> 3, j = kk & 7;
    int lane = hi * 16 + lr;
    size_t dst;
    if (m < 4)      dst = (size_t)m * 24576 + (sg * 2 + cb) * 512 + lane * 8 + j;
    else if (m < 7) dst = 98304 + (size_t)(m - 4) * 36864 + (sg * 12 + cb) * 512 + lane * 8 + j;
    else            dst = 208896 + (size_t)(sg * 6 + cb) * 512 + lane * 8 + j;
    out[dst] = v;
}

// ================= big branches: [N,768] fp32 -> bf16 h cols =================
// 16-row tiles, 4 waves split K (6 chunks each). A read fully CONTIGUOUS
// (12x1KB per wave per tile) -> regs -> bf16 LDS. B frags resident in VGPRs.
// Partial K-sums reduced via LDS scratch. 33 KB LDS -> 3 blocks/CU.
__global__ __launch_bounds__(256, 3) void k_branch(
    const float* __restrict__ des, const float* __restrict__ twt,
    const float* __restrict__ prex, const float* __restrict__ xx,
    const u16* __restrict__ Wf,
    const float* __restrict__ bd, const float* __restrict__ btx,
    const float* __restrict__ btw, const float* __restrict__ btr,
    u16* __restrict__ h)
{
    __shared__ u16 Abuf[16][776];       // 24832 B, row pad 8 u16 (bank offset 4)
    __shared__ float scr[4][16][32];    // 8192 B partial accs

    const int br = blockIdx.y;
    const float* A; const float* bias; int colBase;
    switch (br) {
      case 0:  A = des;  bias = bd;  colBase = 64;  break;
      case 1:  A = twt;  bias = btx; colBase = 96;  break;
      case 2:  A = prex; bias = btw; colBase = 128; break;
      default: A = xx;   bias = btr; colBase = 160; break;
    }

    const int t0 = threadIdx.x, w = t0 >> 6, l = t0 & 63;
    const int hi = l >> 4, lr = l & 15;

    // ---- resident B fragments: wave w's K-window = chunks w*6 .. w*6+5 ----
    bf16x8 Bfr[12];
    {
        const u16* wp = Wf + br * 24576;
        #pragma unroll
        for (int cc = 0; cc < 6; ++cc)
            #pragma unroll
            for (int cb = 0; cb < 2; ++cb)
                Bfr[cc * 2 + cb] = *(const bf16x8*)(wp + ((w * 6 + cc) * 2 + cb) * 512 + l * 8);
    }

    // reduce-phase constants (per thread)
    const int rrow = t0 >> 4;            // 0..15
    const int col0 = (t0 & 15) * 2;      // 0..30 even
    const float bias0 = bias[col0], bias1 = bias[col0 + 1];

    float4 f4[12];
    int tile = blockIdx.x;
    // prologue: issue loads for first tile (wave w's 4 rows = 12 KB contiguous)
    {
        const float* ab = A + (size_t)tile * 12288 + w * 3072 + l * 4;
        #pragma unroll
        for (int i = 0; i < 12; ++i) f4[i] = *(const float4*)(ab + i * 256);
    }

    for (; tile < 3125; tile += 192) {
        asm volatile("s_waitcnt vmcnt(0)" ::: "memory");
        // convert + LDS write (rows w*4 .. w*4+3)
        #pragma unroll
        for (int i = 0; i < 12; ++i) {
            const int rr = i / 3, third = i % 3;
            unsigned plo = (unsigned)f2bf(f4[i].x) | ((unsigned)f2bf(f4[i].y) << 16);
            unsigned phi = (unsigned)f2bf(f4[i].z) | ((unsigned)f2bf(f4[i].w) << 16);
            uint2 pk; pk.x = plo; pk.y = phi;
            *(uint2*)&Abuf[w * 4 + rr][third * 256 + l * 4] = pk;
        }
        // issue next tile's loads (stay in flight across compute)
        const int tnext = tile + 192;
        if (tnext < 3125) {
            const float* ab = A + (size_t)tnext * 12288 + w * 3072 + l * 4;
            #pragma unroll
            for (int i = 0; i < 12; ++i) f4[i] = *(const float4*)(ab + i * 256);
        }
        __syncthreads();

        // compute partial over this wave's K-window
        f32x4 acc[2] = {};
        #pragma unroll
        for (int cc = 0; cc < 6; ++cc) {
            const int cg = w * 6 + cc;
            bf16x8 af = *(const bf16x8*)&Abuf[lr][cg * 32 + hi * 8];
            acc[0] = __builtin_amdgcn_mfma_f32_16x16x32_bf16(af, Bfr[cc * 2 + 0], acc[0], 0, 0, 0);
            acc[1] = __builtin_amdgcn_mfma_f32_16x16x32_bf16(af, Bfr[cc * 2 + 1], acc[1], 0, 0, 0);
        }
        // partials -> scratch (C/D: col = cb*16+lr, row = hi*4+rg)
        #pragma unroll
        for (int cb = 0; cb < 2; ++cb)
            #pragma unroll
            for (int rg = 0; rg < 4; ++rg)
                scr[w][hi * 4 + rg][cb * 16 + lr] = acc[cb][rg];
        __syncthreads();

        // reduce 4 wave-partials, bias + lrelu, store 2 bf16 per thread
        float2 s; s.x = 0.f; s.y = 0.f;
        #pragma unroll
        for (int ww = 0; ww < 4; ++ww) {
            float2 p = *(const float2*)&scr[ww][rrow][col0];
            s.x += p.x; s.y += p.y;
        }
        float v0 = lrelu(s.x + bias0);
        float v1 = lrelu(s.y + bias1);
        unsigned pk = (unsigned)f2bf(v0) | ((unsigned)f2bf(v1) << 16);
        *(unsigned*)&h[((size_t)tile * 16 + rrow) * HD + colBase + col0] = pk;
    }
}

// ================= hidden GEMM: bf16 [N,192] @ W^T -> bf16 [N,192] =================
template<bool BIAS, bool LRELU>
__global__ __launch_bounds__(512) void k_hgemm(
    const u16* __restrict__ A, const u16* __restrict__ Wf,
    const float* __restrict__ bias, u16* __restrict__ out)
{
    __shared__ u16 Bs[36864];
    const int t = threadIdx.x, w = t >> 6, l = t & 63;
    const int hi = l >> 4, lr = l & 15;
    const int rowBase = blockIdx.x * 128;
    {
        const uint4* s_ = (const uint4*)Wf; uint4* d_ = (uint4*)Bs;
        #pragma unroll
        for (int i = 0; i < 9; ++i) d_[i * 512 + t] = s_[i * 512 + t];
    }
    int r0 = rowBase + w * 16 + lr;
    int rowc = r0 < NN ? r0 : NN - 1;
    const u16* ap = A + (size_t)rowc * HD;
    float4 araw[6];
    #pragma unroll
    for (int sg = 0; sg < 6; ++sg) {
        araw[sg] = *(const float4*)(ap + sg * 32 + hi * 8);
        asm volatile("" :: "v"(araw[sg].x), "v"(araw[sg].y), "v"(araw[sg].z), "v"(araw[sg].w));
    }
    __syncthreads();

    f32x4 acc[12] = {};
    #pragma unroll
    for (int sg = 0; sg < 6; ++sg) {
        bf16x8 af = as_bf8(araw[sg]);
        #pragma unroll
        for (int cb = 0; cb < 12; ++cb) {
            bf16x8 bf = *(const bf16x8*)(Bs + (sg * 12 + cb) * 512 + l * 8);
            acc[cb] = __builtin_amdgcn_mfma_f32_16x16x32_bf16(af, bf, acc[cb], 0, 0, 0);
        }
    }

    #pragma unroll
    for (int cb = 0; cb < 12; ++cb) {
        int cl = cb * 16 + lr;
        float bv = BIAS ? bias[cl] : 0.f;
        #pragma unroll
        for (int rg = 0; rg < 4; ++rg) {
            int r = rowBase + w * 16 + hi * 4 + rg;
            if (r < NN) {
                float v = acc[cb][rg] + bv;
                if (LRELU) v = lrelu(v);
                out[(size_t)r * HD + cl] = f2bf(v);
            }
        }
    }
}

// ================= final: em = lrelu(hC @ Wo1^T + b1) fp32 + out = em @ Wo2^T + b2 =================
__global__ __launch_bounds__(512) void k_final(
    const u16* __restrict__ A, const u16* __restrict__ Wf,
    const float* __restrict__ b1, const float* __restrict__ W2,
    const float* __restrict__ b2, float* __restrict__ em, float* __restrict__ out)
{
    __shared__ u16 Bs[18432];
    const int t = threadIdx.x, w = t >> 6, l = t & 63;
    const int hi = l >> 4, lr = l & 15;
    const int rowBase = blockIdx.x * 128;
    {
        const uint4* s_ = (const uint4*)Wf; uint4* d_ = (uint4*)Bs;
        #pragma unroll
        for (int i = 0; i < 5; ++i) { int idx = i * 512 + t; if (idx < 2304) d_[idx] = s_[idx]; }
    }
    int r0 = rowBase + w * 16 + lr;
    int rowc = r0 < NN ? r0 : NN - 1;
    const u16* ap = A + (size_t)rowc * HD;
    float4 araw[6];
    #pragma unroll
    for (int sg = 0; sg < 6; ++sg) {
        araw[sg] = *(const float4*)(ap + sg * 32 + hi * 8);
        asm volatile("" :: "v"(araw[sg].x), "v"(araw[sg].y), "v"(araw[sg].z), "v"(araw[sg].w));
    }
    __syncthreads();

    f32x4 acc[6] = {};
    #pragma unroll
    for (int sg = 0; sg < 6; ++sg) {
        bf16x8 af = as_bf8(araw[sg]);
        #pragma unroll
        for (int cb = 0; cb < 6; ++cb) {
            bf16x8 bf = *(const bf16x8*)(Bs + (sg * 6 + cb) * 512 + l * 8);
            acc[cb] = __builtin_amdgcn_mfma_f32_16x16x32_bf16(af, bf, acc[cb], 0, 0, 0);
        }
    }

    float w2v[2][6], bv[6];
    #pragma unroll
    for (int cb = 0; cb < 6; ++cb) {
        bv[cb] = b1[cb * 16 + lr];
        w2v[0][cb] = W2[cb * 16 + lr];
        w2v[1][cb] = W2[96 + cb * 16 + lr];
    }

    #pragma unroll
    for (int rg = 0; rg < 4; ++rg) {
        int r = rowBase + w * 16 + hi * 4 + rg;
        float o0 = 0.f, o1 = 0.f;
        #pragma unroll
        for (int cb = 0; cb < 6; ++cb) {
            float v = lrelu(acc[cb][rg] + bv[cb]);
            if (r < NN) em[(size_t)r * 96 + cb * 16 + lr] = v;
            o0 += v * w2v[0][cb];
            o1 += v * w2v[1][cb];
        }
        #pragma unroll
        for (int d = 1; d < 16; d <<= 1) {
            o0 += __shfl_xor(o0, d);
            o1 += __shfl_xor(o1, d);
        }
        if (lr == 0 && r < NN) {
            out[r * 2 + 0] = o0 + b2[0];
            out[r * 2 + 1] = o1 + b2[1];
        }
    }
}

// ================= small branches: cols 0..63 =================
__global__ __launch_bounds__(256) void k_small_branch(
    const float* __restrict__ nprop, const float* __restrict__ ncat,
    const float* __restrict__ Wp, const float* __restrict__ bp,
    const float* __restrict__ Wc, const float* __restrict__ bc,
    u16* __restrict__ h)
{
    int idx = blockIdx.x * 256 + threadIdx.x;
    if (idx >= NN * 64) return;
    int row = idx >> 6, c = idx & 63;
    float acc;
    if (c < 32) {
        acc = bp[c];
        #pragma unroll
        for (int k = 0; k < 5; ++k) acc += nprop[row * 5 + k] * Wp[c * 5 + k];
    } else {
        int cc = c - 32;
        acc = bc[cc] + ncat[row] * Wc[cc];
    }
    h[(size_t)row * HD + c] = f2bf(lrelu(acc));
}

// ================= graph structure =================
__global__ void k_count(const int* __restrict__ ei, int* __restrict__ deg)
{
    int e = blockIdx.x * 256 + threadIdx.x;
    if (e < EE) atomicAdd(&deg[ei[EE + e]], 1);
}

__global__ void k_deginv(const int* __restrict__ deg, float* __restrict__ dinv, float* __restrict__ invdeg)
{
    int v = blockIdx.x * 256 + threadIdx.x;
    if (v < NN) {
        float d = (float)(deg[v] + 1);
        dinv[v] = rsqrtf(d);
        invdeg[v] = 1.0f / d;
    }
}

__global__ __launch_bounds__(1024) void k_scan1(const int* __restrict__ deg, int* __restrict__ rp, int* __restrict__ part)
{
    __shared__ int sh[1024];
    int tid = threadIdx.x, i = blockIdx.x * 1024 + tid;
    int x = (i < NN) ? deg[i] : 0;
    sh[tid] = x;
    __syncthreads();
    for (int off = 1; off < 1024; off <<= 1) {
        int y = (tid >= off) ? sh[tid - off] : 0;
        __syncthreads();
        sh[tid] += y;
        __syncthreads();
    }
    if (i < NN) rp[i] = sh[tid] - x;
    if (tid == 1023) part[blockIdx.x] = sh[tid];
}

__global__ void k_scan2(int* part, int nb, int* rp)
{
    if (threadIdx.x == 0 && blockIdx.x == 0) {
        int run = 0;
        for (int b = 0; b < nb; ++b) { int t = part[b]; part[b] = run; run += t; }
        rp[NN] = run;
    }
}

__global__ void k_scan3(int* rp, const int* __restrict__ part)
{
    int i = blockIdx.x * 256 + threadIdx.x;
    if (i < NN) rp[i] += part[i >> 10];
}

__global__ void k_fill(const int* __restrict__ ei, const float* __restrict__ dinv,
                       int* __restrict__ cursor, int* __restrict__ cs, float* __restrict__ nrm)
{
    int e = blockIdx.x * 256 + threadIdx.x;
    if (e >= EE) return;
    int s = ei[e], d = ei[EE + e];
    int pos = atomicAdd(&cursor[d], 1);
    cs[pos] = s;
    nrm[pos] = dinv[s] * dinv[d];
}

// ================= GCN aggregation =================
__global__ __launch_bounds__(240) void k_agg(const u16* __restrict__ hW,
    const int* __restrict__ rp, const int* __restrict__ cs, const float* __restrict__ nrm,
    const float* __restrict__ invdeg, const float* __restrict__ bias, u16* __restrict__ out)
{
    int v = blockIdx.x * 5 + threadIdx.y;
    int f0 = threadIdx.x * 4;
    int s0 = rp[v], s1 = rp[v + 1];
    float4 bv = *reinterpret_cast<const float4*>(bias + f0);
    ushort4 hv = *reinterpret_cast<const ushort4*>(hW + (size_t)v * HD + f0);
    float idg = invdeg[v];
    float a0 = bf2f(hv.x) * idg + bv.x;
    float a1 = bf2f(hv.y) * idg + bv.y;
    float a2 = bf2f(hv.z) * idg + bv.z;
    float a3 = bf2f(hv.w) * idg + bv.w;
    int i = s0;
    for (; i + 4 <= s1; i += 4) {
        int c0 = cs[i], c1 = cs[i+1], c2 = cs[i+2], c3 = cs[i+3];
        float n0 = nrm[i], n1 = nrm[i+1], n2 = nrm[i+2], n3 = nrm[i+3];
        ushort4 g0 = *reinterpret_cast<const ushort4*>(hW + (size_t)c0 * HD + f0);
        ushort4 g1 = *reinterpret_cast<const ushort4*>(hW + (size_t)c1 * HD + f0);
        ushort4 g2 = *reinterpret_cast<const ushort4*>(hW + (size_t)c2 * HD + f0);
        ushort4 g3 = *reinterpret_cast<const ushort4*>(hW + (size_t)c3 * HD + f0);
        a0 += bf2f(g0.x) * n0; a1 += bf2f(g0.y) * n0; a2 += bf2f(g0.z) * n0; a3 += bf2f(g0.w) * n0;
        a0 += bf2f(g1.x) * n1; a1 += bf2f(g1.y) * n1; a2 += bf2f(g1.z) * n1; a3 += bf2f(g1.w) * n1;
        a0 += bf2f(g2.x) * n2; a1 += bf2f(g2.y) * n2; a2 += bf2f(g2.z) * n2; a3 += bf2f(g2.w) * n2;
        a0 += bf2f(g3.x) * n3; a1 += bf2f(g3.y) * n3; a2 += bf2f(g3.z) * n3; a3 += bf2f(g3.w) * n3;
    }
    for (; i < s1; ++i) {
        int c = cs[i]; float n = nrm[i];
        ushort4 g = *reinterpret_cast<const ushort4*>(hW + (size_t)c * HD + f0);
        a0 += bf2f(g.x) * n; a1 += bf2f(g.y) * n; a2 += bf2f(g.z) * n; a3 += bf2f(g.w) * n;
    }
    ushort4 o;
    o.x = f2bf(a0); o.y = f2bf(a1); o.z = f2bf(a2); o.w = f2bf(a3);
    *reinterpret_cast<ushort4*>(out + (size_t)v * HD + f0) = o;
}

extern "C" void kernel_launch(void* const* d_in, const int* in_sizes, int n_in,
                              void* d_out, int out_size, void* d_ws, size_t ws_size,
                              hipStream_t stream)
{
    const float* pre_x = (const float*)d_in[0];
    const float* x     = (const float*)d_in[1];
    const int*   ei    = (const int*)d_in[2];
    const float* nprop = (const float*)d_in[4];
    const float* ncat  = (const float*)d_in[5];
    const float* des   = (const float*)d_in[6];
    const float* twt   = (const float*)d_in[7];
    const float* W_des  = (const float*)d_in[8],  *b_des  = (const float*)d_in[9];
    const float* W_tw   = (const float*)d_in[10], *b_tw   = (const float*)d_in[11];
    const float* W_tr   = (const float*)d_in[12], *b_tr   = (const float*)d_in[13];
    const float* W_prop = (const float*)d_in[14], *b_prop = (const float*)d_in[15];
    const float* W_cat  = (const float*)d_in[16], *b_cat  = (const float*)d_in[17];
    const float* W_text = (const float*)d_in[18], *b_text = (const float*)d_in[19];
    const float* W_in   = (const float*)d_in[20], *b_in   = (const float*)d_in[21];
    const float* W_c1   = (const float*)d_in[22], *b_c1   = (const float*)d_in[23];
    const float* W_c2   = (const float*)d_in[24], *b_c2   = (const float*)d_in[25];
    const float* W_o1   = (const float*)d_in[26], *b_o1   = (const float*)d_in[27];
    const float* W_o2   = (const float*)d_in[28], *b_o2   = (const float*)d_in[29];

    char* base = (char*)d_ws;
    size_t off = 0;
    auto alloc = [&](size_t bytes) -> char* {
        char* p = base + off;
        off = (off + bytes + 255) & ~(size_t)255;
        return p;
    };
    u16*   hA     = (u16*)alloc((size_t)NN * HD * 2);
    u16*   hB     = (u16*)alloc((size_t)NN * HD * 2);
    u16*   hC     = (u16*)alloc((size_t)NN * HD * 2);
    u16*   Wprep  = (u16*)alloc((size_t)227328 * 2);
    float* dinv   = (float*)alloc((size_t)NN * 4);
    float* invdeg = (float*)alloc((size_t)NN * 4);
    int*   deg    = (int*)alloc((size_t)NN * 4);
    int*   rp     = (int*)alloc((size_t)(NN + 1) * 4);
    int*   cursor = (int*)alloc((size_t)NN * 4);
    int*   part   = (int*)alloc(64 * 4);
    int*   cs     = (int*)alloc((size_t)EE * 4);
    float* nrm    = (float*)alloc((size_t)EE * 4);
    (void)ws_size; (void)in_sizes; (void)n_in; (void)out_size;

    float* outp = (float*)d_out;            // [N,2]
    float* em   = outp + (size_t)NN * 2;    // [N,96] fp32

    const int rb     = (NN + 255) / 256;    // 196
    const int rb128  = (NN + 127) / 128;    // 391
    const int eb     = (EE + 255) / 256;    // 3125
    const int nb1024 = (NN + 1023) / 1024;  // 49

    // ---- weight prep + graph structure ----
    hipMemsetAsync(deg, 0, (size_t)NN * 4, stream);
    hipLaunchKernelGGL(k_prep, dim3(144, 8), dim3(256), 0, stream,
        W_des, W_text, W_tw, W_tr, W_in, W_c1, W_c2, W_o1, Wprep);
    hipLaunchKernelGGL(k_count,  dim3(eb), dim3(256), 0, stream, ei, deg);
    hipLaunchKernelGGL(k_deginv, dim3(rb), dim3(256), 0, stream, deg, dinv, invdeg);
    hipLaunchKernelGGL(k_scan1,  dim3(nb1024), dim3(1024), 0, stream, deg, rp, part);
    hipLaunchKernelGGL(k_scan2,  dim3(1), dim3(1), 0, stream, part, nb1024, rp);
    hipLaunchKernelGGL(k_scan3,  dim3(rb), dim3(256), 0, stream, rp, part);
    hipMemcpyAsync(cursor, rp, (size_t)NN * 4, hipMemcpyDeviceToDevice, stream);
    hipLaunchKernelGGL(k_fill,   dim3(eb), dim3(256), 0, stream, ei, dinv, cursor, cs, nrm);

    // ---- feature path ----
    hipLaunchKernelGGL(k_branch, dim3(192, 4), dim3(256), 0, stream,
        des, twt, pre_x, x, Wprep, b_des, b_text, b_tw, b_tr, hA);
    hipLaunchKernelGGL(k_small_branch, dim3((NN * 64 + 255) / 256), dim3(256), 0, stream,
        nprop, ncat, W_prop, b_prop, W_cat, b_cat, hA);

    hipLaunchKernelGGL((k_hgemm<true, true>),   dim3(rb128), dim3(512), 0, stream,
        hA, Wprep + 98304, b_in, hB);
    hipLaunchKernelGGL((k_hgemm<false, false>), dim3(rb128), dim3(512), 0, stream,
        hB, Wprep + 98304 + 36864, nullptr, hC);
    hipLaunchKernelGGL(k_agg, dim3(NN / 5), dim3(48, 5), 0, stream, hC, rp, cs, nrm, invdeg, b_c1, hA);
    hipLaunchKernelGGL((k_hgemm<false, false>), dim3(rb128), dim3(512), 0, stream,
        hA, Wprep + 98304 + 2 * 36864, nullptr, hB);
    hipLaunchKernelGGL(k_agg, dim3(NN / 5), dim3(48, 5), 0, stream, hB, rp, cs, nrm, invdeg, b_c2, hC);

    hipLaunchKernelGGL(k_final, dim3(rb128), dim3(512), 0, stream,
        hC, Wprep + 208896, b_o1, W_o2, b_o2, em, outp);
}